// Round 1
// baseline (611.704 us; speedup 1.0000x reference)
//
#include <hip/hip_runtime.h>
#include <math.h>

#define B_   8
#define CIN  768
#define HH   32
#define WW   32
#define HID  128
#define NA   36
#define PP   1024   /* HH*WW */

#define DOT4(acc, a4, w4) \
  acc = fmaf((a4).x,(w4).x, fmaf((a4).y,(w4).y, fmaf((a4).z,(w4).z, fmaf((a4).w,(w4).w,(acc)))))

// ---------------------------------------------------------------- init output
__global__ __launch_bounds__(256) void init_out_k(float* out, const float* b2) {
  int i = blockIdx.x * 256 + threadIdx.x;
  if (i < B_ * NA) out[i] = b2[0];
}

// ------------------------------------------------- rotation corner helper
// Matches reference affine_grid + grid_sample (align_corners=False, zeros pad).
__device__ inline void rot_corners(float ct, float st, int y, int x,
                                   float w[4], int p[4]) {
  float xn = (2.0f * x + 1.0f) * (1.0f / 32.0f) - 1.0f;
  float yn = (2.0f * y + 1.0f) * (1.0f / 32.0f) - 1.0f;
  float gx = ct * xn - st * yn;
  float gy = st * xn + ct * yn;
  float ix = ((gx + 1.0f) * 32.0f - 1.0f) * 0.5f;
  float iy = ((gy + 1.0f) * 32.0f - 1.0f) * 0.5f;
  float x0f = floorf(ix), y0f = floorf(iy);
  float wx = ix - x0f, wy = iy - y0f;
  int x0 = (int)x0f, y0 = (int)y0f;
  int x1 = x0 + 1, y1 = y0 + 1;
  float vx0 = (x0 >= 0 && x0 < 32) ? 1.0f : 0.0f;
  float vx1 = (x1 >= 0 && x1 < 32) ? 1.0f : 0.0f;
  float vy0 = (y0 >= 0 && y0 < 32) ? 1.0f : 0.0f;
  float vy1 = (y1 >= 0 && y1 < 32) ? 1.0f : 0.0f;
  int cx0 = min(max(x0, 0), 31), cx1 = min(max(x1, 0), 31);
  int cy0 = min(max(y0, 0), 31), cy1 = min(max(y1, 0), 31);
  w[0] = (1.0f - wx) * (1.0f - wy) * vx0 * vy0;  p[0] = (cy0 << 5) + cx0;
  w[1] = wx * (1.0f - wy) * vx1 * vy0;           p[1] = (cy0 << 5) + cx1;
  w[2] = (1.0f - wx) * wy * vx0 * vy1;           p[2] = (cy1 << 5) + cx0;
  w[3] = wx * wy * vx1 * vy1;                    p[3] = (cy1 << 5) + cx1;
}

// ------------------------------------------------- shared 64-K-chunk GEMM core
__device__ inline void gemm_chunk64(const float (*A)[68], const float (*Wl)[68],
                                    int xg, int og, float acc[4][4]) {
  #pragma unroll
  for (int k = 0; k < 64; k += 4) {
    float4 a0 = *(const float4*)&A[xg      ][k];
    float4 a1 = *(const float4*)&A[xg +  8][k];
    float4 a2 = *(const float4*)&A[xg + 16][k];
    float4 a3 = *(const float4*)&A[xg + 24][k];
    float4 w0 = *(const float4*)&Wl[og      ][k];
    float4 w1 = *(const float4*)&Wl[og + 32][k];
    float4 w2 = *(const float4*)&Wl[og + 64][k];
    float4 w3 = *(const float4*)&Wl[og + 96][k];
    DOT4(acc[0][0], a0, w0); DOT4(acc[0][1], a1, w0);
    DOT4(acc[0][2], a2, w0); DOT4(acc[0][3], a3, w0);
    DOT4(acc[1][0], a0, w1); DOT4(acc[1][1], a1, w1);
    DOT4(acc[1][2], a2, w1); DOT4(acc[1][3], a3, w1);
    DOT4(acc[2][0], a0, w2); DOT4(acc[2][1], a1, w2);
    DOT4(acc[2][2], a2, w2); DOT4(acc[2][3], a3, w2);
    DOT4(acc[3][0], a0, w3); DOT4(acc[3][1], a1, w3);
    DOT4(acc[3][2], a2, w3); DOT4(acc[3][3], a3, w3);
  }
}

// ---------------------------------------------------------- projection + L2 norm
// g[b,p,o] = l2norm_o( sum_c Wg[o,c]*gal[b,c,p] ); same for q.
// block = one (b,y) row x {gallery,query}; out layout [b][p][128] (o contiguous)
__global__ __launch_bounds__(256, 2) void proj_norm_k(
    const float* __restrict__ gal, const float* __restrict__ qry,
    const float* __restrict__ Wg, const float* __restrict__ Wq,
    float* __restrict__ gout, float* __restrict__ qout) {
  __shared__ __align__(16) float A[32][68];
  __shared__ __align__(16) float Wl[128][68];
  __shared__ float red[32][32];
  __shared__ float inv[32];
  int b = blockIdx.x >> 5, y = blockIdx.x & 31;
  const float* src = blockIdx.y ? qry : gal;
  const float* Wm  = blockIdx.y ? Wq  : Wg;
  float* dst       = blockIdx.y ? qout : gout;
  int tid = threadIdx.x;
  int xg = tid & 7, og = tid >> 3;   // x = xg + 8i, o = og + 32j
  float acc[4][4] = {{0.f,0.f,0.f,0.f},{0.f,0.f,0.f,0.f},
                     {0.f,0.f,0.f,0.f},{0.f,0.f,0.f,0.f}};
  for (int cc = 0; cc < CIN; cc += 64) {
    #pragma unroll
    for (int i = 0; i < 8; i++) {          // A tile: 64c x 32x (transposed store)
      int e = tid + (i << 8);
      int cl = e >> 5, x = e & 31;
      A[x][cl] = src[((b * CIN + cc + cl) << 10) + (y << 5) + x];
    }
    #pragma unroll
    for (int i = 0; i < 32; i++) {         // W tile: 128o x 64c
      int e = tid + (i << 8);
      int o = e >> 6, cl = e & 63;
      Wl[o][cl] = Wm[o * CIN + cc + cl];
    }
    __syncthreads();
    gemm_chunk64(A, Wl, xg, og, acc);
    __syncthreads();
  }
  // L2 norm over o per x
  #pragma unroll
  for (int i = 0; i < 4; i++) {
    float ss = acc[0][i]*acc[0][i] + acc[1][i]*acc[1][i]
             + acc[2][i]*acc[2][i] + acc[3][i]*acc[3][i];
    red[xg + 8*i][og] = ss;
  }
  __syncthreads();
  if (tid < 32) {
    float ssum = 0.f;
    #pragma unroll
    for (int k = 0; k < 32; k++) ssum += red[tid][k];
    inv[tid] = 1.0f / fmaxf(sqrtf(ssum), 1e-12f);
  }
  __syncthreads();
  int pbase = (b << 10) + (y << 5);
  #pragma unroll
  for (int i = 0; i < 4; i++) {
    float sc = inv[xg + 8*i];
    #pragma unroll
    for (int j = 0; j < 4; j++)
      dst[(pbase + xg + 8*i) * HID + og + 32*j] = acc[j][i] * sc;
  }
}

// ------------------------------------------- per-position 128x128 projections
// base[b,p,o] = sum_c W1[:, 0:128][o,c]*g[b,p,c]  (blockIdx.y==0)
// qp  [b,p,o] = sum_c W1[:,128:256][o,c]*q[b,p,c] (blockIdx.y==1)
__global__ __launch_bounds__(256, 2) void posproj_k(
    const float* __restrict__ g, const float* __restrict__ q,
    const float* __restrict__ W1, float* __restrict__ base, float* __restrict__ qp) {
  __shared__ __align__(16) float A[32][68];
  __shared__ __align__(16) float Wl[128][68];
  int b = blockIdx.x >> 5, y = blockIdx.x & 31;
  const float* src = blockIdx.y ? q : g;
  float* dst       = blockIdx.y ? qp : base;
  int woff         = blockIdx.y ? 128 : 0;
  int tid = threadIdx.x;
  int xg = tid & 7, og = tid >> 3;
  int pbase = (b << 10) + (y << 5);
  float acc[4][4] = {{0.f,0.f,0.f,0.f},{0.f,0.f,0.f,0.f},
                     {0.f,0.f,0.f,0.f},{0.f,0.f,0.f,0.f}};
  for (int cc = 0; cc < HID; cc += 64) {
    #pragma unroll
    for (int i = 0; i < 8; i++) {          // A: 32 pos x 64 c (rows contiguous)
      int e = tid + (i << 8);
      int x = e >> 6, cl = e & 63;
      A[x][cl] = src[(pbase + x) * HID + cc + cl];
    }
    #pragma unroll
    for (int i = 0; i < 32; i++) {
      int e = tid + (i << 8);
      int o = e >> 6, cl = e & 63;
      Wl[o][cl] = W1[o * 512 + woff + cc + cl];
    }
    __syncthreads();
    gemm_chunk64(A, Wl, xg, og, acc);
    __syncthreads();
  }
  #pragma unroll
  for (int i = 0; i < 4; i++)
    #pragma unroll
    for (int j = 0; j < 4; j++)
      dst[(pbase + xg + 8*i) * HID + og + 32*j] = acc[j][i];
}

// ------------------------------------------------------------------- main
// block = (y-row, b, angle). Builds X=[g.*qr ; |g-qr|] (32x256) in LDS, GEMM
// against W1[:,256:512] (K chunks of 32), epilogue fuses base + blended qp +
// b1 + ReLU + W2 dot + block reduce + atomicAdd.
__global__ __launch_bounds__(256, 2) void main_k(
    const float* __restrict__ gbuf, const float* __restrict__ qbuf,
    const float* __restrict__ basebuf, const float* __restrict__ qpbuf,
    const float* __restrict__ W1, const float* __restrict__ b1,
    const float* __restrict__ W2, const float* __restrict__ angles,
    float* __restrict__ out) {
  __shared__ __align__(16) float X[32][260];   // [x][k], k<128: g*qr, k>=128: |g-qr|
  __shared__ __align__(16) float Wl[128][36];
  __shared__ float redw[4];
  int y = blockIdx.x, b = blockIdx.y, a = blockIdx.z;
  int tid = threadIdx.x;
  float th = angles[a] * 0.017453292519943295f;
  float ct = cosf(th), st = sinf(th);
  const float* qB = qbuf + b * (PP * HID);
  const float* gB = gbuf + b * (PP * HID);

  // ---- fill X: bilinear gather of qr (4 corners, float4 over o)
  #pragma unroll
  for (int t = 0; t < 4; t++) {
    int e = tid + (t << 8);
    int x = e >> 5;
    int o = (e & 31) << 2;
    float w[4]; int p[4];
    rot_corners(ct, st, y, x, w, p);
    float qr0 = 0.f, qr1 = 0.f, qr2 = 0.f, qr3 = 0.f;
    #pragma unroll
    for (int k = 0; k < 4; k++) {
      float4 c4 = *(const float4*)(qB + p[k] * HID + o);
      float wk = w[k];
      qr0 = fmaf(wk, c4.x, qr0);
      qr1 = fmaf(wk, c4.y, qr1);
      qr2 = fmaf(wk, c4.z, qr2);
      qr3 = fmaf(wk, c4.w, qr3);
    }
    float4 g4 = *(const float4*)(gB + (((y << 5) + x) * HID) + o);
    X[x][o + 0] = g4.x * qr0;
    X[x][o + 1] = g4.y * qr1;
    X[x][o + 2] = g4.z * qr2;
    X[x][o + 3] = g4.w * qr3;
    X[x][HID + o + 0] = fabsf(g4.x - qr0);
    X[x][HID + o + 1] = fabsf(g4.y - qr1);
    X[x][HID + o + 2] = fabsf(g4.z - qr2);
    X[x][HID + o + 3] = fabsf(g4.w - qr3);
  }

  // ---- GEMM: acc[o tile][x tile] over K=256 (W1 cols 256..512)
  int xg = tid & 7, og = tid >> 3;
  float acc[4][4] = {{0.f,0.f,0.f,0.f},{0.f,0.f,0.f,0.f},
                     {0.f,0.f,0.f,0.f},{0.f,0.f,0.f,0.f}};
  for (int k0 = 0; k0 < 256; k0 += 32) {
    __syncthreads();   // first iter: guards X fill; later: guards prev Wl reads
    #pragma unroll
    for (int i = 0; i < 16; i++) {
      int e = tid + (i << 8);
      int o = e >> 5, kk = e & 31;
      Wl[o][kk] = W1[o * 512 + 256 + k0 + kk];
    }
    __syncthreads();
    #pragma unroll
    for (int kk = 0; kk < 32; kk += 4) {
      float4 a0 = *(const float4*)&X[xg      ][k0 + kk];
      float4 a1 = *(const float4*)&X[xg +  8][k0 + kk];
      float4 a2 = *(const float4*)&X[xg + 16][k0 + kk];
      float4 a3 = *(const float4*)&X[xg + 24][k0 + kk];
      float4 w0 = *(const float4*)&Wl[og      ][kk];
      float4 w1 = *(const float4*)&Wl[og + 32][kk];
      float4 w2 = *(const float4*)&Wl[og + 64][kk];
      float4 w3 = *(const float4*)&Wl[og + 96][kk];
      DOT4(acc[0][0], a0, w0); DOT4(acc[0][1], a1, w0);
      DOT4(acc[0][2], a2, w0); DOT4(acc[0][3], a3, w0);
      DOT4(acc[1][0], a0, w1); DOT4(acc[1][1], a1, w1);
      DOT4(acc[1][2], a2, w1); DOT4(acc[1][3], a3, w1);
      DOT4(acc[2][0], a0, w2); DOT4(acc[2][1], a1, w2);
      DOT4(acc[2][2], a2, w2); DOT4(acc[2][3], a3, w2);
      DOT4(acc[3][0], a0, w3); DOT4(acc[3][1], a1, w3);
      DOT4(acc[3][2], a2, w3); DOT4(acc[3][3], a3, w3);
    }
  }

  // ---- epilogue: h = base + qp_blend + b1 + acc ; relu ; dot with W2
  const float* baseB = basebuf + b * (PP * HID);
  const float* qpB   = qpbuf   + b * (PP * HID);
  float s = 0.f;
  #pragma unroll
  for (int i = 0; i < 4; i++) {
    int x = xg + 8*i;
    float w[4]; int p[4];
    rot_corners(ct, st, y, x, w, p);
    int pp = (y << 5) + x;
    #pragma unroll
    for (int j = 0; j < 4; j++) {
      int o = og + 32*j;
      float qpv = w[0] * qpB[p[0] * HID + o] + w[1] * qpB[p[1] * HID + o]
                + w[2] * qpB[p[2] * HID + o] + w[3] * qpB[p[3] * HID + o];
      float h = baseB[pp * HID + o] + qpv + b1[o] + acc[j][i];
      h = fmaxf(h, 0.f);
      s = fmaf(W2[o], h, s);
    }
  }
  // block reduction
  #pragma unroll
  for (int off = 32; off > 0; off >>= 1) s += __shfl_down(s, off, 64);
  int lane = tid & 63, wv = tid >> 6;
  if (lane == 0) redw[wv] = s;
  __syncthreads();
  if (tid == 0) {
    float tot = redw[0] + redw[1] + redw[2] + redw[3];
    atomicAdd(&out[b * NA + a], tot * (1.0f / 1024.0f));
  }
}

// --------------------------------------------------------------------- launch
extern "C" void kernel_launch(void* const* d_in, const int* in_sizes, int n_in,
                              void* d_out, int out_size, void* d_ws, size_t ws_size,
                              hipStream_t stream) {
  const float* gal = (const float*)d_in[0];
  const float* qry = (const float*)d_in[1];
  const float* Wg  = (const float*)d_in[2];
  const float* Wq  = (const float*)d_in[3];
  const float* W1  = (const float*)d_in[4];
  const float* b1  = (const float*)d_in[5];
  const float* W2  = (const float*)d_in[6];
  const float* b2  = (const float*)d_in[7];
  const float* ang = (const float*)d_in[8];
  float* out = (float*)d_out;
  float* wsf = (float*)d_ws;
  float* g    = wsf;                 // [8][1024][128]
  float* q    = wsf + (1u << 20);
  float* base = wsf + (2u << 20);
  float* qp   = wsf + (3u << 20);

  hipLaunchKernelGGL(init_out_k, dim3(2), dim3(256), 0, stream, out, b2);
  hipLaunchKernelGGL(proj_norm_k, dim3(256, 2), dim3(256), 0, stream,
                     gal, qry, Wg, Wq, g, q);
  hipLaunchKernelGGL(posproj_k, dim3(256, 2), dim3(256), 0, stream,
                     g, q, W1, base, qp);
  hipLaunchKernelGGL(main_k, dim3(32, 8, 36), dim3(256), 0, stream,
                     g, q, base, qp, W1, b1, W2, ang, out);
}

// Round 2
// 228.767 us; speedup vs baseline: 2.6739x; 2.6739x over previous
//
#include <hip/hip_runtime.h>
#include <math.h>

#define B_   8
#define CIN  768
#define HID  128
#define NA   36
#define PP   1024

typedef __attribute__((ext_vector_type(8))) short s16x8;
typedef __attribute__((ext_vector_type(4))) float f32x4;

__device__ inline unsigned short f2bf(float f) {
  union { float f; unsigned int u; } v; v.f = f;
  unsigned int r = v.u + 0x7fffu + ((v.u >> 16) & 1u);
  return (unsigned short)(r >> 16);
}
__device__ inline float bf2f(unsigned short h) {
  union { unsigned int u; float f; } v; v.u = ((unsigned int)h) << 16;
  return v.f;
}
union LD16 { float4 f4; unsigned short us[8]; };

__device__ inline s16x8 pack8(float4 lo, float4 hi) {
  s16x8 s;
  s[0] = (short)f2bf(lo.x); s[1] = (short)f2bf(lo.y);
  s[2] = (short)f2bf(lo.z); s[3] = (short)f2bf(lo.w);
  s[4] = (short)f2bf(hi.x); s[5] = (short)f2bf(hi.y);
  s[6] = (short)f2bf(hi.z); s[7] = (short)f2bf(hi.w);
  return s;
}

// ---------------------------------------------------------------- init output
__global__ __launch_bounds__(256) void init_out_k(float* out, const float* b2) {
  int i = blockIdx.x * 256 + threadIdx.x;
  if (i < B_ * NA) out[i] = b2[0];
}

// ------------------------------------------------- rotation corner helper
// Matches reference affine_grid + grid_sample (align_corners=False, zeros pad).
// Identical arithmetic to round-1 (which matched ref exactly).
__device__ inline void rot_corners(float ct, float st, int y, int x,
                                   float w[4], int p[4]) {
  float xn = (2.0f * x + 1.0f) * (1.0f / 32.0f) - 1.0f;
  float yn = (2.0f * y + 1.0f) * (1.0f / 32.0f) - 1.0f;
  float gx = ct * xn - st * yn;
  float gy = st * xn + ct * yn;
  float ix = ((gx + 1.0f) * 32.0f - 1.0f) * 0.5f;
  float iy = ((gy + 1.0f) * 32.0f - 1.0f) * 0.5f;
  float x0f = floorf(ix), y0f = floorf(iy);
  float wx = ix - x0f, wy = iy - y0f;
  int x0 = (int)x0f, y0 = (int)y0f;
  int x1 = x0 + 1, y1 = y0 + 1;
  float vx0 = (x0 >= 0 && x0 < 32) ? 1.0f : 0.0f;
  float vx1 = (x1 >= 0 && x1 < 32) ? 1.0f : 0.0f;
  float vy0 = (y0 >= 0 && y0 < 32) ? 1.0f : 0.0f;
  float vy1 = (y1 >= 0 && y1 < 32) ? 1.0f : 0.0f;
  int cx0 = min(max(x0, 0), 31), cx1 = min(max(x1, 0), 31);
  int cy0 = min(max(y0, 0), 31), cy1 = min(max(y1, 0), 31);
  w[0] = (1.0f - wx) * (1.0f - wy) * vx0 * vy0;  p[0] = (cy0 << 5) + cx0;
  w[1] = wx * (1.0f - wy) * vx1 * vy0;           p[1] = (cy0 << 5) + cx1;
  w[2] = (1.0f - wx) * wy * vx0 * vy1;           p[2] = (cy1 << 5) + cx0;
  w[3] = wx * wy * vx1 * vy1;                    p[3] = (cy1 << 5) + cx1;
}

#define MFMA(a, b, c) __builtin_amdgcn_mfma_f32_16x16x32_bf16((a), (b), (c), 0, 0, 0)

// ---------------------------------------------------------- projection + L2 norm
// g[b,p,o] = l2norm_o( Wg @ gal[b,:,p] ), bf16 MFMA, output bf16 [b][p][128].
// grid (256, 2): x -> (b,y), y -> {gallery, query}. 256 threads, 4 waves.
__global__ __launch_bounds__(256) void proj_norm_k(
    const float* __restrict__ gal, const float* __restrict__ qry,
    const float* __restrict__ Wg, const float* __restrict__ Wq,
    unsigned short* __restrict__ gout, unsigned short* __restrict__ qout) {
  __shared__ short As[32 * 72];     // A tile [x][c] bf16, stride 72 (144B)
  __shared__ short Wls[128 * 72];   // W tile [o][c] bf16
  __shared__ float red[32 * 8];
  __shared__ float inv[32];
  int b = blockIdx.x >> 5, y = blockIdx.x & 31;
  const float* src = blockIdx.y ? qry : gal;
  const float* Wm  = blockIdx.y ? Wq  : Wg;
  unsigned short* dst = blockIdx.y ? qout : gout;
  int tid = threadIdx.x;
  int lane = tid & 63, wv = tid >> 6;
  int q = lane >> 4, lr = lane & 15;
  int nq = wv * 32;
  f32x4 acc[2][2];
  #pragma unroll
  for (int i = 0; i < 2; i++)
    #pragma unroll
    for (int j = 0; j < 2; j++) acc[i][j] = (f32x4){0.f, 0.f, 0.f, 0.f};

  int wo = tid >> 1, wh = (tid & 1) * 32;   // W staging coords
  for (int cc = 0; cc < CIN; cc += 64) {
    // A: 64 channels x 32 x, transposed store to [x][c] bf16
    #pragma unroll
    for (int i = 0; i < 8; i++) {
      int e = tid + (i << 8);
      int cl = e >> 5, x = e & 31;
      As[x * 72 + cl] = (short)f2bf(src[((b * CIN + cc + cl) << 10) + (y << 5) + x]);
    }
    // W: 128 o x 64 c
    #pragma unroll
    for (int j = 0; j < 4; j++) {
      int kk = wh + j * 8;
      float4 lo = *(const float4*)(Wm + wo * CIN + cc + kk);
      float4 hi = *(const float4*)(Wm + wo * CIN + cc + kk + 4);
      *(s16x8*)&Wls[wo * 72 + kk] = pack8(lo, hi);
    }
    __syncthreads();
    #pragma unroll
    for (int k0 = 0; k0 < 64; k0 += 32) {
      s16x8 a0 = *(const s16x8*)&As[(lr) * 72 + k0 + q * 8];
      s16x8 a1 = *(const s16x8*)&As[(16 + lr) * 72 + k0 + q * 8];
      s16x8 b0 = *(const s16x8*)&Wls[(nq + lr) * 72 + k0 + q * 8];
      s16x8 b1v = *(const s16x8*)&Wls[(nq + 16 + lr) * 72 + k0 + q * 8];
      acc[0][0] = MFMA(a0, b0, acc[0][0]); acc[0][1] = MFMA(a0, b1v, acc[0][1]);
      acc[1][0] = MFMA(a1, b0, acc[1][0]); acc[1][1] = MFMA(a1, b1v, acc[1][1]);
    }
    __syncthreads();
  }
  // sum of squares over o per position m
  #pragma unroll
  for (int mi = 0; mi < 2; mi++) {
    #pragma unroll
    for (int r = 0; r < 4; r++) {
      float ss = acc[mi][0][r] * acc[mi][0][r] + acc[mi][1][r] * acc[mi][1][r];
      ss += __shfl_xor(ss, 1); ss += __shfl_xor(ss, 2);
      ss += __shfl_xor(ss, 4); ss += __shfl_xor(ss, 8);
      if (lr == 0) red[(mi * 16 + q * 4 + r) * 8 + wv] = ss;
    }
  }
  __syncthreads();
  if (tid < 32) {
    float ssum = red[tid * 8] + red[tid * 8 + 1] + red[tid * 8 + 2] + red[tid * 8 + 3];
    inv[tid] = 1.0f / fmaxf(sqrtf(ssum), 1e-12f);
  }
  __syncthreads();
  int pbase = (b << 10) + (y << 5);
  #pragma unroll
  for (int mi = 0; mi < 2; mi++) {
    #pragma unroll
    for (int r = 0; r < 4; r++) {
      int m = mi * 16 + q * 4 + r;
      float sc = inv[m];
      #pragma unroll
      for (int ni = 0; ni < 2; ni++) {
        int n = nq + ni * 16 + lr;
        dst[(pbase + m) * HID + n] = f2bf(acc[mi][ni][r] * sc);
      }
    }
  }
}

// ------------------------------------------- base = W1[:,0:128] @ g, fp32 out
__global__ __launch_bounds__(256) void posproj_k(
    const unsigned short* __restrict__ g, const float* __restrict__ W1,
    float* __restrict__ base) {
  __shared__ short As[32 * 136];    // [x][c] bf16, stride 136 (272B)
  __shared__ short Wls[128 * 136];
  int b = blockIdx.x >> 5, y = blockIdx.x & 31;
  int tid = threadIdx.x;
  int lane = tid & 63, wv = tid >> 6;
  int q = lane >> 4, lr = lane & 15;
  int nq = wv * 32;
  int pbase = (b << 10) + (y << 5);
  // stage A: straight copy of 32 rows x 128 ch bf16
  #pragma unroll
  for (int i = 0; i < 2; i++) {
    int j = tid + (i << 8);
    int row = j >> 4, col = (j & 15) << 3;
    *(float4*)&As[row * 136 + col] = *(const float4*)(g + (pbase + row) * HID + col);
  }
  // stage W1g
  {
    int o = tid >> 1, k0 = (tid & 1) * 64;
    #pragma unroll
    for (int j = 0; j < 8; j++) {
      int kk = k0 + j * 8;
      float4 lo = *(const float4*)(W1 + o * 512 + kk);
      float4 hi = *(const float4*)(W1 + o * 512 + kk + 4);
      *(s16x8*)&Wls[o * 136 + kk] = pack8(lo, hi);
    }
  }
  __syncthreads();
  f32x4 acc[2][2];
  #pragma unroll
  for (int i = 0; i < 2; i++)
    #pragma unroll
    for (int j = 0; j < 2; j++) acc[i][j] = (f32x4){0.f, 0.f, 0.f, 0.f};
  #pragma unroll
  for (int k0 = 0; k0 < 128; k0 += 32) {
    s16x8 a0 = *(const s16x8*)&As[(lr) * 136 + k0 + q * 8];
    s16x8 a1 = *(const s16x8*)&As[(16 + lr) * 136 + k0 + q * 8];
    s16x8 b0 = *(const s16x8*)&Wls[(nq + lr) * 136 + k0 + q * 8];
    s16x8 b1v = *(const s16x8*)&Wls[(nq + 16 + lr) * 136 + k0 + q * 8];
    acc[0][0] = MFMA(a0, b0, acc[0][0]); acc[0][1] = MFMA(a0, b1v, acc[0][1]);
    acc[1][0] = MFMA(a1, b0, acc[1][0]); acc[1][1] = MFMA(a1, b1v, acc[1][1]);
  }
  #pragma unroll
  for (int mi = 0; mi < 2; mi++)
    #pragma unroll
    for (int r = 0; r < 4; r++) {
      int m = mi * 16 + q * 4 + r;
      #pragma unroll
      for (int ni = 0; ni < 2; ni++) {
        int n = nq + ni * 16 + lr;
        base[(pbase + m) * HID + n] = acc[mi][ni][r];
      }
    }
}

// ------------------------------------------------------------------- main
// grid (16 y-pairs, 8 b, 6 angle-groups), 512 threads (8 waves).
// W1[:,128:512] bf16 resident in LDS across 6 angles; per angle build
// X=[qr | g.*qr | |g-qr|] (64 pos x 384 k) in LDS, MFMA, fused epilogue.
__global__ __launch_bounds__(512, 2) void main_k(
    const unsigned short* __restrict__ g_bf, const unsigned short* __restrict__ q_bf,
    const float* __restrict__ basebuf, const float* __restrict__ W1,
    const float* __restrict__ b1, const float* __restrict__ W2,
    const float* __restrict__ angles, float* __restrict__ out) {
  __shared__ short Xs[64 * 392];     // 50176 B  (stride 392 sh = 784 B, ≡4 mod 32 words)
  __shared__ short W1l[128 * 392];   // 100352 B
  __shared__ float redw[8];
  int y0 = blockIdx.x * 2;
  int b  = blockIdx.y;
  int tid = threadIdx.x;
  int lane = tid & 63, wv = tid >> 6;
  int q = lane >> 4, lr = lane & 15;
  int mh = (wv >> 2) * 32;           // M-half of this wave
  int nq = (wv & 3) * 32;            // N-quarter

  // ---- stage W1[:,128:512] -> bf16 LDS (once)
  {
    int o = tid >> 2, kq = tid & 3;
    #pragma unroll
    for (int j = 0; j < 12; j++) {
      int kk = kq * 96 + j * 8;
      float4 lo = *(const float4*)(W1 + o * 512 + 128 + kk);
      float4 hi = *(const float4*)(W1 + o * 512 + 128 + kk + 4);
      *(s16x8*)&W1l[o * 392 + kk] = pack8(lo, hi);
    }
  }

  // ---- preload base + b1 into registers (angle-invariant lane mapping)
  float bacc[2][2][4];
  float w2v[2];
  #pragma unroll
  for (int ni = 0; ni < 2; ni++) w2v[ni] = W2[nq + ni * 16 + lr];
  #pragma unroll
  for (int mi = 0; mi < 2; mi++)
    #pragma unroll
    for (int r = 0; r < 4; r++) {
      int m = mh + mi * 16 + q * 4 + r;
      int pos = ((y0 + (m >> 5)) << 5) + (m & 31);
      #pragma unroll
      for (int ni = 0; ni < 2; ni++) {
        int n = nq + ni * 16 + lr;
        bacc[mi][ni][r] = basebuf[((b << 10) + pos) * HID + n] + b1[n];
      }
    }

  // build-phase constants
  int bm = tid >> 3, ks = tid & 7;           // position row, channel slot
  int byy = bm >> 5, bx = bm & 31, by = y0 + byy;
  const unsigned short* qB = q_bf + (size_t)(b << 10) * HID;
  const unsigned short* gB = g_bf + (size_t)((b << 10) + (by << 5) + bx) * HID;

  for (int it = 0; it < 6; it++) {
    int a = blockIdx.z * 6 + it;
    float th = angles[a] * 0.017453292519943295f;
    float ct = cosf(th), st = sinf(th);

    // ---- build X
    {
      float w4[4]; int p4[4];
      rot_corners(ct, st, by, bx, w4, p4);
      const unsigned short* c0p = qB + p4[0] * HID;
      const unsigned short* c1p = qB + p4[1] * HID;
      const unsigned short* c2p = qB + p4[2] * HID;
      const unsigned short* c3p = qB + p4[3] * HID;
      #pragma unroll
      for (int cg = 0; cg < 2; cg++) {
        int c = ks * 16 + cg * 8;
        LD16 u0, u1, u2, u3, gg;
        u0.f4 = *(const float4*)(c0p + c);
        u1.f4 = *(const float4*)(c1p + c);
        u2.f4 = *(const float4*)(c2p + c);
        u3.f4 = *(const float4*)(c3p + c);
        gg.f4 = *(const float4*)(gB + c);
        s16x8 sq, sm, sa;
        #pragma unroll
        for (int i = 0; i < 8; i++) {
          float qr = w4[0] * bf2f(u0.us[i]) + w4[1] * bf2f(u1.us[i])
                   + w4[2] * bf2f(u2.us[i]) + w4[3] * bf2f(u3.us[i]);
          float gv = bf2f(gg.us[i]);
          sq[i] = (short)f2bf(qr);
          sm[i] = (short)f2bf(gv * qr);
          sa[i] = (short)f2bf(fabsf(gv - qr));
        }
        *(s16x8*)&Xs[bm * 392 + c] = sq;
        *(s16x8*)&Xs[bm * 392 + 128 + c] = sm;
        *(s16x8*)&Xs[bm * 392 + 256 + c] = sa;
      }
    }
    __syncthreads();   // X (and, first iter, W1l) visible

    // ---- MFMA: 32x32 tile per wave, K=384
    f32x4 acc[2][2];
    #pragma unroll
    for (int i = 0; i < 2; i++)
      #pragma unroll
      for (int j = 0; j < 2; j++) acc[i][j] = (f32x4){0.f, 0.f, 0.f, 0.f};
    #pragma unroll
    for (int k0 = 0; k0 < 384; k0 += 32) {
      s16x8 a0 = *(const s16x8*)&Xs[(mh + lr) * 392 + k0 + q * 8];
      s16x8 a1 = *(const s16x8*)&Xs[(mh + 16 + lr) * 392 + k0 + q * 8];
      s16x8 b0 = *(const s16x8*)&W1l[(nq + lr) * 392 + k0 + q * 8];
      s16x8 b1v = *(const s16x8*)&W1l[(nq + 16 + lr) * 392 + k0 + q * 8];
      acc[0][0] = MFMA(a0, b0, acc[0][0]); acc[0][1] = MFMA(a0, b1v, acc[0][1]);
      acc[1][0] = MFMA(a1, b0, acc[1][0]); acc[1][1] = MFMA(a1, b1v, acc[1][1]);
    }

    // ---- epilogue: relu(acc + base + b1) . W2, reduce, atomic
    float s = 0.f;
    #pragma unroll
    for (int mi = 0; mi < 2; mi++)
      #pragma unroll
      for (int ni = 0; ni < 2; ni++)
        #pragma unroll
        for (int r = 0; r < 4; r++)
          s = fmaf(w2v[ni], fmaxf(acc[mi][ni][r] + bacc[mi][ni][r], 0.f), s);
    #pragma unroll
    for (int off = 32; off > 0; off >>= 1) s += __shfl_down(s, off, 64);
    if (lane == 0) redw[wv] = s;
    __syncthreads();   // also guards X rebuild next iteration
    if (tid == 0) {
      float tot = redw[0] + redw[1] + redw[2] + redw[3]
                + redw[4] + redw[5] + redw[6] + redw[7];
      atomicAdd(&out[b * NA + a], tot * (1.0f / 1024.0f));
    }
  }
}

// --------------------------------------------------------------------- launch
extern "C" void kernel_launch(void* const* d_in, const int* in_sizes, int n_in,
                              void* d_out, int out_size, void* d_ws, size_t ws_size,
                              hipStream_t stream) {
  const float* gal = (const float*)d_in[0];
  const float* qry = (const float*)d_in[1];
  const float* Wg  = (const float*)d_in[2];
  const float* Wq  = (const float*)d_in[3];
  const float* W1  = (const float*)d_in[4];
  const float* b1  = (const float*)d_in[5];
  const float* W2  = (const float*)d_in[6];
  const float* b2  = (const float*)d_in[7];
  const float* ang = (const float*)d_in[8];
  float* out = (float*)d_out;
  unsigned short* g_bf = (unsigned short*)d_ws;                 // 2 MB
  unsigned short* q_bf = g_bf + (B_ * PP * HID);                // 2 MB
  float* base = (float*)((char*)d_ws + 4u * 1024 * 1024);       // 4 MB

  hipLaunchKernelGGL(init_out_k, dim3(2), dim3(256), 0, stream, out, b2);
  hipLaunchKernelGGL(proj_norm_k, dim3(256, 2), dim3(256), 0, stream,
                     gal, qry, Wg, Wq, g_bf, q_bf);
  hipLaunchKernelGGL(posproj_k, dim3(256), dim3(256), 0, stream, g_bf, W1, base);
  hipLaunchKernelGGL(main_k, dim3(16, 8, 6), dim3(512), 0, stream,
                     g_bf, q_bf, base, W1, b1, W2, ang, out);
}

// Round 3
// 198.788 us; speedup vs baseline: 3.0772x; 1.1508x over previous
//
#include <hip/hip_runtime.h>
#include <math.h>

#define B_   8
#define CIN  768
#define HID  128
#define NA   36
#define PP   1024

typedef __attribute__((ext_vector_type(8))) short s16x8;
typedef __attribute__((ext_vector_type(4))) float f32x4;

__device__ inline unsigned short f2bf(float f) {
  union { float f; unsigned int u; } v; v.f = f;
  unsigned int r = v.u + 0x7fffu + ((v.u >> 16) & 1u);
  return (unsigned short)(r >> 16);
}
__device__ inline float bf2f(unsigned short h) {
  union { unsigned int u; float f; } v; v.u = ((unsigned int)h) << 16;
  return v.f;
}
union LD16 { float4 f4; unsigned short us[8]; };

__device__ inline s16x8 pack8(float4 lo, float4 hi) {
  s16x8 s;
  s[0] = (short)f2bf(lo.x); s[1] = (short)f2bf(lo.y);
  s[2] = (short)f2bf(lo.z); s[3] = (short)f2bf(lo.w);
  s[4] = (short)f2bf(hi.x); s[5] = (short)f2bf(hi.y);
  s[6] = (short)f2bf(hi.z); s[7] = (short)f2bf(hi.w);
  return s;
}

#define MFMA(a, b, c) __builtin_amdgcn_mfma_f32_16x16x32_bf16((a), (b), (c), 0, 0, 0)

// ------------------------------------------------- rotation corner helper
__device__ inline void rot_corners(float ct, float st, int y, int x,
                                   float w[4], int p[4]) {
  float xn = (2.0f * x + 1.0f) * (1.0f / 32.0f) - 1.0f;
  float yn = (2.0f * y + 1.0f) * (1.0f / 32.0f) - 1.0f;
  float gx = ct * xn - st * yn;
  float gy = st * xn + ct * yn;
  float ix = ((gx + 1.0f) * 32.0f - 1.0f) * 0.5f;
  float iy = ((gy + 1.0f) * 32.0f - 1.0f) * 0.5f;
  float x0f = floorf(ix), y0f = floorf(iy);
  float wx = ix - x0f, wy = iy - y0f;
  int x0 = (int)x0f, y0 = (int)y0f;
  int x1 = x0 + 1, y1 = y0 + 1;
  float vx0 = (x0 >= 0 && x0 < 32) ? 1.0f : 0.0f;
  float vx1 = (x1 >= 0 && x1 < 32) ? 1.0f : 0.0f;
  float vy0 = (y0 >= 0 && y0 < 32) ? 1.0f : 0.0f;
  float vy1 = (y1 >= 0 && y1 < 32) ? 1.0f : 0.0f;
  int cx0 = min(max(x0, 0), 31), cx1 = min(max(x1, 0), 31);
  int cy0 = min(max(y0, 0), 31), cy1 = min(max(y1, 0), 31);
  w[0] = (1.0f - wx) * (1.0f - wy) * vx0 * vy0;  p[0] = (cy0 << 5) + cx0;
  w[1] = wx * (1.0f - wy) * vx1 * vy0;           p[1] = (cy0 << 5) + cx1;
  w[2] = (1.0f - wx) * wy * vx0 * vy1;           p[2] = (cy1 << 5) + cx0;
  w[3] = wx * wy * vx1 * vy1;                    p[3] = (cy1 << 5) + cx1;
}

// -------------------------------------------------------------------- prep
// Converts Wg/Wq/W1 fp32 -> bf16 once; initializes out[288] = b2.
__global__ __launch_bounds__(256) void prep_k(
    const float* __restrict__ Wg, const float* __restrict__ Wq,
    const float* __restrict__ W1, const float* __restrict__ b2,
    unsigned short* __restrict__ Wg_bf, unsigned short* __restrict__ Wq_bf,
    unsigned short* __restrict__ W1_bf, float* __restrict__ out) {
  int idx = blockIdx.x * 256 + threadIdx.x;
  if (idx < B_ * NA) out[idx] = b2[0];
  if (idx < 32768) {                     // 262144 bf16 elems / 8
    int e = idx * 8;
    const float* src; unsigned short* dst; int off;
    if (e < 98304)       { src = Wg; dst = Wg_bf; off = e; }
    else if (e < 196608) { src = Wq; dst = Wq_bf; off = e - 98304; }
    else                 { src = W1; dst = W1_bf; off = e - 196608; }
    float4 lo = *(const float4*)(src + off);
    float4 hi = *(const float4*)(src + off + 4);
    *(s16x8*)(dst + off) = pack8(lo, hi);
  }
}

// ---------------------------------------------------------- projection + L2 norm
// grid (128, 2): x -> (b, ypair); y -> {gallery, query}. 512 threads (8 waves).
// M=64 positions, N=128, K=768. A staged transposed from fp32 [c,p] via LDS.
__global__ __launch_bounds__(512) void proj_norm_k(
    const float* __restrict__ gal, const float* __restrict__ qry,
    const unsigned short* __restrict__ Wg_bf, const unsigned short* __restrict__ Wq_bf,
    unsigned short* __restrict__ gout, unsigned short* __restrict__ qout) {
  __shared__ short As[64 * 72];     // [p][c] bf16
  __shared__ short Wls[128 * 72];   // [o][c] bf16
  __shared__ float red[64 * 4];
  __shared__ float inv[64];
  int b = blockIdx.x >> 4, yp = blockIdx.x & 15;
  const float* src = blockIdx.y ? qry : gal;
  const unsigned short* Wm = blockIdx.y ? Wq_bf : Wg_bf;
  unsigned short* dst = blockIdx.y ? qout : gout;
  int tid = threadIdx.x;
  int lane = tid & 63, wv = tid >> 6;
  int q = lane >> 4, lr = lane & 15;
  int mh = (wv >> 2) * 32, nq = (wv & 3) * 32;
  int pbase = (b << 10) + yp * 64;
  f32x4 acc[2][2];
  #pragma unroll
  for (int i = 0; i < 2; i++)
    #pragma unroll
    for (int j = 0; j < 2; j++) acc[i][j] = (f32x4){0.f, 0.f, 0.f, 0.f};

  int ach = tid >> 3, apg = tid & 7;          // A staging: channel, pos-group
  int wo = tid >> 2, wseg = tid & 3;          // W staging
  for (int cc = 0; cc < CIN; cc += 64) {
    // A: 64 ch x 64 pos fp32, coalesced float4 along p, transposed store
    {
      const float* sp = src + (((size_t)(b * CIN + cc + ach)) << 10) + yp * 64 + apg * 8;
      float4 f0 = *(const float4*)sp;
      float4 f1 = *(const float4*)(sp + 4);
      int p0 = apg * 8;
      As[(p0 + 0) * 72 + ach] = (short)f2bf(f0.x);
      As[(p0 + 1) * 72 + ach] = (short)f2bf(f0.y);
      As[(p0 + 2) * 72 + ach] = (short)f2bf(f0.z);
      As[(p0 + 3) * 72 + ach] = (short)f2bf(f0.w);
      As[(p0 + 4) * 72 + ach] = (short)f2bf(f1.x);
      As[(p0 + 5) * 72 + ach] = (short)f2bf(f1.y);
      As[(p0 + 6) * 72 + ach] = (short)f2bf(f1.z);
      As[(p0 + 7) * 72 + ach] = (short)f2bf(f1.w);
    }
    // W: 128 o x 64 c bf16, b128 copies
    *(s16x8*)&Wls[wo * 72 + wseg * 16]     = *(const s16x8*)(Wm + wo * CIN + cc + wseg * 16);
    *(s16x8*)&Wls[wo * 72 + wseg * 16 + 8] = *(const s16x8*)(Wm + wo * CIN + cc + wseg * 16 + 8);
    __syncthreads();
    #pragma unroll
    for (int k0 = 0; k0 < 64; k0 += 32) {
      s16x8 a0 = *(const s16x8*)&As[(mh + lr) * 72 + k0 + q * 8];
      s16x8 a1 = *(const s16x8*)&As[(mh + 16 + lr) * 72 + k0 + q * 8];
      s16x8 b0 = *(const s16x8*)&Wls[(nq + lr) * 72 + k0 + q * 8];
      s16x8 b1v = *(const s16x8*)&Wls[(nq + 16 + lr) * 72 + k0 + q * 8];
      acc[0][0] = MFMA(a0, b0, acc[0][0]); acc[0][1] = MFMA(a0, b1v, acc[0][1]);
      acc[1][0] = MFMA(a1, b0, acc[1][0]); acc[1][1] = MFMA(a1, b1v, acc[1][1]);
    }
    __syncthreads();
  }
  // sum of squares over o per position m
  #pragma unroll
  for (int mi = 0; mi < 2; mi++) {
    #pragma unroll
    for (int r = 0; r < 4; r++) {
      float ss = acc[mi][0][r] * acc[mi][0][r] + acc[mi][1][r] * acc[mi][1][r];
      ss += __shfl_xor(ss, 1); ss += __shfl_xor(ss, 2);
      ss += __shfl_xor(ss, 4); ss += __shfl_xor(ss, 8);
      if (lr == 0) red[(mh + mi * 16 + q * 4 + r) * 4 + (wv & 3)] = ss;
    }
  }
  __syncthreads();
  if (tid < 64) {
    float ssum = red[tid * 4] + red[tid * 4 + 1] + red[tid * 4 + 2] + red[tid * 4 + 3];
    inv[tid] = 1.0f / fmaxf(sqrtf(ssum), 1e-12f);
  }
  __syncthreads();
  #pragma unroll
  for (int mi = 0; mi < 2; mi++) {
    #pragma unroll
    for (int r = 0; r < 4; r++) {
      int m = mh + mi * 16 + q * 4 + r;
      float sc = inv[m];
      #pragma unroll
      for (int ni = 0; ni < 2; ni++) {
        int n = nq + ni * 16 + lr;
        dst[(pbase + m) * HID + n] = f2bf(acc[mi][ni][r] * sc);
      }
    }
  }
}

// ----------------------------- baseb1 = W1[:,0:128] @ g + b1, fp32 out
__global__ __launch_bounds__(256) void posproj_k(
    const unsigned short* __restrict__ g, const unsigned short* __restrict__ W1_bf,
    const float* __restrict__ b1, float* __restrict__ baseb1) {
  __shared__ short As[32 * 136];
  __shared__ short Wls[128 * 136];
  int b = blockIdx.x >> 5, y = blockIdx.x & 31;
  int tid = threadIdx.x;
  int lane = tid & 63, wv = tid >> 6;
  int q = lane >> 4, lr = lane & 15;
  int nq = wv * 32;
  int pbase = (b << 10) + (y << 5);
  {
    int row = tid >> 3, col = (tid & 7) * 16;
    *(s16x8*)&As[row * 136 + col]     = *(const s16x8*)(g + (pbase + row) * HID + col);
    *(s16x8*)&As[row * 136 + col + 8] = *(const s16x8*)(g + (pbase + row) * HID + col + 8);
  }
  {
    int o = tid >> 1, half = (tid & 1) * 64;
    #pragma unroll
    for (int j = 0; j < 8; j++) {
      int kk = half + j * 8;
      *(s16x8*)&Wls[o * 136 + kk] = *(const s16x8*)(W1_bf + o * 512 + kk);
    }
  }
  __syncthreads();
  f32x4 acc[2][2];
  #pragma unroll
  for (int i = 0; i < 2; i++)
    #pragma unroll
    for (int j = 0; j < 2; j++) acc[i][j] = (f32x4){0.f, 0.f, 0.f, 0.f};
  #pragma unroll
  for (int k0 = 0; k0 < 128; k0 += 32) {
    s16x8 a0 = *(const s16x8*)&As[(lr) * 136 + k0 + q * 8];
    s16x8 a1 = *(const s16x8*)&As[(16 + lr) * 136 + k0 + q * 8];
    s16x8 b0 = *(const s16x8*)&Wls[(nq + lr) * 136 + k0 + q * 8];
    s16x8 b1v = *(const s16x8*)&Wls[(nq + 16 + lr) * 136 + k0 + q * 8];
    acc[0][0] = MFMA(a0, b0, acc[0][0]); acc[0][1] = MFMA(a0, b1v, acc[0][1]);
    acc[1][0] = MFMA(a1, b0, acc[1][0]); acc[1][1] = MFMA(a1, b1v, acc[1][1]);
  }
  #pragma unroll
  for (int mi = 0; mi < 2; mi++)
    #pragma unroll
    for (int r = 0; r < 4; r++) {
      int m = mi * 16 + q * 4 + r;
      #pragma unroll
      for (int ni = 0; ni < 2; ni++) {
        int n = nq + ni * 16 + lr;
        baseb1[(pbase + m) * HID + n] = acc[mi][ni][r] + b1[n];
      }
    }
}

// ------------------------------------------------------------------- main
// grid (32 y, 8 b, 6 agroups) = 1536 blocks x 256 thr; 3 blocks/CU.
// W1[:,128:512] bf16 B-fragments in REGISTERS (96 VGPR), reused over 6 angles.
// LDS = X only (32 x 384, 25 KB). Per angle: build X, 1 barrier, 48 MFMA/wave,
// fused epilogue with preloaded base+b1.
__global__ __launch_bounds__(256, 3) void main_k(
    const unsigned short* __restrict__ g_bf, const unsigned short* __restrict__ q_bf,
    const float* __restrict__ baseb1, const unsigned short* __restrict__ W1_bf,
    const float* __restrict__ W2, const float* __restrict__ angles,
    float* __restrict__ out) {
  __shared__ short Xs[32 * 392];     // 25088 B
  __shared__ float redw[4];
  int y = blockIdx.x, b = blockIdx.y;
  int tid = threadIdx.x;
  int lane = tid & 63, wv = tid >> 6;
  int q = lane >> 4, lr = lane & 15;
  int nq = wv * 32;

  // ---- B-fragments from global bf16 W1 (cols 128..512), once per block
  s16x8 bfr[12][2];
  #pragma unroll
  for (int s = 0; s < 12; s++)
    #pragma unroll
    for (int ni = 0; ni < 2; ni++) {
      int o = nq + ni * 16 + lr;
      bfr[s][ni] = *(const s16x8*)(W1_bf + o * 512 + 128 + s * 32 + q * 8);
    }

  // ---- preload base+b1 and W2 (angle-invariant lane mapping)
  float bacc[2][2][4];
  float w2v[2];
  #pragma unroll
  for (int ni = 0; ni < 2; ni++) w2v[ni] = W2[nq + ni * 16 + lr];
  #pragma unroll
  for (int mi = 0; mi < 2; mi++)
    #pragma unroll
    for (int r = 0; r < 4; r++) {
      int m = mi * 16 + q * 4 + r;
      #pragma unroll
      for (int ni = 0; ni < 2; ni++)
        bacc[mi][ni][r] = baseb1[((b << 10) + (y << 5) + m) * HID + nq + ni * 16 + lr];
    }

  // build-phase constants: 8 threads per position row
  int bx = tid >> 3, ks = tid & 7;
  const unsigned short* qB = q_bf + (size_t)(b << 10) * HID;
  const unsigned short* gB = g_bf + (size_t)((b << 10) + (y << 5) + bx) * HID;

  for (int it = 0; it < 6; it++) {
    int a = blockIdx.z * 6 + it;
    float th = angles[a] * 0.017453292519943295f;
    float ct = cosf(th), st = sinf(th);

    // ---- build X = [qr | g.*qr | |g-qr|]  (32 pos x 384)
    {
      float w4[4]; int p4[4];
      rot_corners(ct, st, y, bx, w4, p4);
      const unsigned short* c0p = qB + p4[0] * HID;
      const unsigned short* c1p = qB + p4[1] * HID;
      const unsigned short* c2p = qB + p4[2] * HID;
      const unsigned short* c3p = qB + p4[3] * HID;
      #pragma unroll
      for (int cg = 0; cg < 2; cg++) {
        int c = ks * 16 + cg * 8;
        LD16 u0, u1, u2, u3, gg;
        u0.f4 = *(const float4*)(c0p + c);
        u1.f4 = *(const float4*)(c1p + c);
        u2.f4 = *(const float4*)(c2p + c);
        u3.f4 = *(const float4*)(c3p + c);
        gg.f4 = *(const float4*)(gB + c);
        s16x8 sq, sm, sa;
        #pragma unroll
        for (int i = 0; i < 8; i++) {
          float qr = w4[0] * bf2f(u0.us[i]) + w4[1] * bf2f(u1.us[i])
                   + w4[2] * bf2f(u2.us[i]) + w4[3] * bf2f(u3.us[i]);
          float gv = bf2f(gg.us[i]);
          sq[i] = (short)f2bf(qr);
          sm[i] = (short)f2bf(gv * qr);
          sa[i] = (short)f2bf(fabsf(gv - qr));
        }
        *(s16x8*)&Xs[bx * 392 + c] = sq;
        *(s16x8*)&Xs[bx * 392 + 128 + c] = sm;
        *(s16x8*)&Xs[bx * 392 + 256 + c] = sa;
      }
    }
    __syncthreads();

    // ---- MFMA: 32x32 tile per wave (nq columns), K=384, B from registers
    f32x4 acc[2][2];
    #pragma unroll
    for (int i = 0; i < 2; i++)
      #pragma unroll
      for (int j = 0; j < 2; j++) acc[i][j] = (f32x4){0.f, 0.f, 0.f, 0.f};
    #pragma unroll
    for (int s = 0; s < 12; s++) {
      s16x8 a0 = *(const s16x8*)&Xs[(lr) * 392 + s * 32 + q * 8];
      s16x8 a1 = *(const s16x8*)&Xs[(16 + lr) * 392 + s * 32 + q * 8];
      acc[0][0] = MFMA(a0, bfr[s][0], acc[0][0]);
      acc[0][1] = MFMA(a0, bfr[s][1], acc[0][1]);
      acc[1][0] = MFMA(a1, bfr[s][0], acc[1][0]);
      acc[1][1] = MFMA(a1, bfr[s][1], acc[1][1]);
    }

    // ---- epilogue: relu(acc + base + b1) . W2, reduce, atomic
    float s = 0.f;
    #pragma unroll
    for (int mi = 0; mi < 2; mi++)
      #pragma unroll
      for (int ni = 0; ni < 2; ni++)
        #pragma unroll
        for (int r = 0; r < 4; r++)
          s = fmaf(w2v[ni], fmaxf(acc[mi][ni][r] + bacc[mi][ni][r], 0.f), s);
    #pragma unroll
    for (int off = 32; off > 0; off >>= 1) s += __shfl_down(s, off, 64);
    if (lane == 0) redw[wv] = s;
    __syncthreads();   // guards redw AND Xs reuse next iteration
    if (tid == 0) {
      float tot = redw[0] + redw[1] + redw[2] + redw[3];
      atomicAdd(&out[b * NA + a], tot * (1.0f / 1024.0f));
    }
  }
}

// --------------------------------------------------------------------- launch
extern "C" void kernel_launch(void* const* d_in, const int* in_sizes, int n_in,
                              void* d_out, int out_size, void* d_ws, size_t ws_size,
                              hipStream_t stream) {
  const float* gal = (const float*)d_in[0];
  const float* qry = (const float*)d_in[1];
  const float* Wg  = (const float*)d_in[2];
  const float* Wq  = (const float*)d_in[3];
  const float* W1  = (const float*)d_in[4];
  const float* b1  = (const float*)d_in[5];
  const float* W2  = (const float*)d_in[6];
  const float* b2  = (const float*)d_in[7];
  const float* ang = (const float*)d_in[8];
  float* out = (float*)d_out;
  char* ws = (char*)d_ws;
  unsigned short* g_bf  = (unsigned short*)ws;                        // 2 MB
  unsigned short* q_bf  = (unsigned short*)(ws + (2u << 20));         // 2 MB
  float*          baseb1= (float*)(ws + (4u << 20));                  // 4 MB
  unsigned short* Wg_bf = (unsigned short*)(ws + (8u << 20));         // 192 KB
  unsigned short* Wq_bf = (unsigned short*)(ws + (8u << 20) + 196608);
  unsigned short* W1_bf = (unsigned short*)(ws + (8u << 20) + 393216);

  hipLaunchKernelGGL(prep_k, dim3(128), dim3(256), 0, stream,
                     Wg, Wq, W1, b2, Wg_bf, Wq_bf, W1_bf, out);
  hipLaunchKernelGGL(proj_norm_k, dim3(128, 2), dim3(512), 0, stream,
                     gal, qry, Wg_bf, Wq_bf, g_bf, q_bf);
  hipLaunchKernelGGL(posproj_k, dim3(256), dim3(256), 0, stream,
                     g_bf, W1_bf, b1, baseb1);
  hipLaunchKernelGGL(main_k, dim3(32, 8, 6), dim3(256), 0, stream,
                     g_bf, q_bf, baseb1, W1_bf, W2, ang, out);
}

// Round 5
// 174.725 us; speedup vs baseline: 3.5010x; 1.1377x over previous
//
#include <hip/hip_runtime.h>
#include <math.h>

#define B_   8
#define CIN  768
#define HID  128
#define NA   36
#define PP   1024

typedef _Float16 f16;
typedef __attribute__((ext_vector_type(2))) _Float16 f16x2;
typedef __attribute__((ext_vector_type(4))) _Float16 f16x4;
typedef __attribute__((ext_vector_type(8))) _Float16 f16x8;
typedef __attribute__((ext_vector_type(4))) float f32x4;

#define MFMA16(a, b, c) __builtin_amdgcn_mfma_f32_16x16x32_f16((a), (b), (c), 0, 0, 0)

// cvt_pkrtz returns __fp16x2; bit-cast to our _Float16x2
__device__ inline f16x2 pkrtz(float a, float b) {
  union { __fp16 __attribute__((ext_vector_type(2))) r; f16x2 h; } u;
  u.r = __builtin_amdgcn_cvt_pkrtz(a, b);
  return u.h;
}

// ------------------------------------------------- rotation corner helper
// Matches reference affine_grid + grid_sample (align_corners=False, zeros pad).
__device__ inline void rot_corners(float ct, float st, int y, int x,
                                   float w[4], int p[4]) {
  float xn = (2.0f * x + 1.0f) * (1.0f / 32.0f) - 1.0f;
  float yn = (2.0f * y + 1.0f) * (1.0f / 32.0f) - 1.0f;
  float gx = ct * xn - st * yn;
  float gy = st * xn + ct * yn;
  float ix = ((gx + 1.0f) * 32.0f - 1.0f) * 0.5f;
  float iy = ((gy + 1.0f) * 32.0f - 1.0f) * 0.5f;
  float x0f = floorf(ix), y0f = floorf(iy);
  float wx = ix - x0f, wy = iy - y0f;
  int x0 = (int)x0f, y0 = (int)y0f;
  int x1 = x0 + 1, y1 = y0 + 1;
  float vx0 = (x0 >= 0 && x0 < 32) ? 1.0f : 0.0f;
  float vx1 = (x1 >= 0 && x1 < 32) ? 1.0f : 0.0f;
  float vy0 = (y0 >= 0 && y0 < 32) ? 1.0f : 0.0f;
  float vy1 = (y1 >= 0 && y1 < 32) ? 1.0f : 0.0f;
  int cx0 = min(max(x0, 0), 31), cx1 = min(max(x1, 0), 31);
  int cy0 = min(max(y0, 0), 31), cy1 = min(max(y1, 0), 31);
  w[0] = (1.0f - wx) * (1.0f - wy) * vx0 * vy0;  p[0] = (cy0 << 5) + cx0;
  w[1] = wx * (1.0f - wy) * vx1 * vy0;           p[1] = (cy0 << 5) + cx1;
  w[2] = (1.0f - wx) * wy * vx0 * vy1;           p[2] = (cy1 << 5) + cx0;
  w[3] = wx * wy * vx1 * vy1;                    p[3] = (cy1 << 5) + cx1;
}

// -------------------------------------------------------------------- prep
// Converts Wg/Wq/W1 fp32 -> f16 (RNE) once; initializes out[288] = b2.
__global__ __launch_bounds__(256) void prep_k(
    const float* __restrict__ Wg, const float* __restrict__ Wq,
    const float* __restrict__ W1, const float* __restrict__ b2,
    f16* __restrict__ Wg_h, f16* __restrict__ Wq_h,
    f16* __restrict__ W1_h, float* __restrict__ out) {
  int idx = blockIdx.x * 256 + threadIdx.x;
  if (idx < B_ * NA) out[idx] = b2[0];
  if (idx < 32768) {                     // 262144 f16 elems / 8
    int e = idx * 8;
    const float* src; f16* dst; int off;
    if (e < 98304)       { src = Wg; dst = Wg_h; off = e; }
    else if (e < 196608) { src = Wq; dst = Wq_h; off = e - 98304; }
    else                 { src = W1; dst = W1_h; off = e - 196608; }
    float4 lo = *(const float4*)(src + off);
    float4 hi = *(const float4*)(src + off + 4);
    f16x8 h;
    h[0] = (f16)lo.x; h[1] = (f16)lo.y; h[2] = (f16)lo.z; h[3] = (f16)lo.w;
    h[4] = (f16)hi.x; h[5] = (f16)hi.y; h[6] = (f16)hi.z; h[7] = (f16)hi.w;
    *(f16x8*)(dst + off) = h;
  }
}

// ---------------------------------------------------------- projection + L2 norm
// C[o,p] = Wm @ img. W is the MFMA A-operand (staged in LDS per K-chunk);
// the image is the B-operand, loaded DIRECTLY from its natural [c][p] global
// layout as coalesced scalar dwords + v_cvt_pkrtz (no LDS transpose).
// grid (32, 8, 2): pblk (32 positions), b, {gallery,query}. 128 thr (2 waves).
__global__ __launch_bounds__(128) void proj_norm_k(
    const float* __restrict__ gal, const float* __restrict__ qry,
    const f16* __restrict__ Wg_h, const f16* __restrict__ Wq_h,
    f16* __restrict__ gout, f16* __restrict__ qout) {
  __shared__ f16 Ws[128 * 72];       // [o][c-chunk] f16
  __shared__ f16 bounce[32 * 136];   // [p][o] staging for coalesced output
  int pblk = blockIdx.x, b = blockIdx.y;
  const float* src = blockIdx.z ? qry : gal;
  const f16* Wm = blockIdx.z ? Wq_h : Wg_h;
  f16* dst = blockIdx.z ? qout : gout;
  int tid = threadIdx.x, lane = tid & 63, wv = tid >> 6;
  int q = lane >> 4, lr = lane & 15;
  int p0 = pblk * 32 + wv * 16;
  const float* imgB = src + (size_t)b * CIN * PP;
  f32x4 acc[8];
  #pragma unroll
  for (int t = 0; t < 8; t++) acc[t] = (f32x4){0.f, 0.f, 0.f, 0.f};

  for (int cc = 0; cc < CIN; cc += 64) {
    #pragma unroll
    for (int j = 0; j < 8; j++)      // stage W chunk: 128 o x 64 c
      *(f16x8*)&Ws[tid * 72 + j * 8] = *(const f16x8*)(Wm + tid * CIN + cc + j * 8);
    __syncthreads();
    #pragma unroll
    for (int ks = 0; ks < 64; ks += 32) {
      // B-frag: img[c = cc+ks+q*8+j][p0+lr], fp32 -> packed f16 (RTZ; bias
      // cancels through the l2 norm)
      const float* ip = imgB + (size_t)(cc + ks + q * 8) * PP + p0 + lr;
      float v0 = ip[0], v1 = ip[PP], v2 = ip[2 * PP], v3 = ip[3 * PP];
      float v4 = ip[4 * PP], v5 = ip[5 * PP], v6 = ip[6 * PP], v7 = ip[7 * PP];
      union { f16x8 v; f16x2 h[4]; } bf;
      bf.h[0] = pkrtz(v0, v1);
      bf.h[1] = pkrtz(v2, v3);
      bf.h[2] = pkrtz(v4, v5);
      bf.h[3] = pkrtz(v6, v7);
      #pragma unroll
      for (int t = 0; t < 8; t++) {
        f16x8 af = *(const f16x8*)&Ws[(t * 16 + lr) * 72 + ks + q * 8];
        acc[t] = MFMA16(af, bf.v, acc[t]);
      }
    }
    __syncthreads();
  }
  // l2 norm over o: each lane holds 32 o-values at fixed p=lr; finish across q
  float ss = 0.f;
  #pragma unroll
  for (int t = 0; t < 8; t++)
    #pragma unroll
    for (int r = 0; r < 4; r++) ss += acc[t][r] * acc[t][r];
  ss += __shfl_xor(ss, 16);
  ss += __shfl_xor(ss, 32);
  float inv = 1.0f / fmaxf(sqrtf(ss), 1e-12f);
  int prow = wv * 16 + lr;
  #pragma unroll
  for (int t = 0; t < 8; t++) {     // o = t*16 + q*4 + r  (C/D layout)
    f16x4 h;
    h[0] = (f16)(acc[t][0] * inv); h[1] = (f16)(acc[t][1] * inv);
    h[2] = (f16)(acc[t][2] * inv); h[3] = (f16)(acc[t][3] * inv);
    *(f16x4*)&bounce[prow * 136 + t * 16 + q * 4] = h;
  }
  __syncthreads();
  int row = tid >> 2, seg = tid & 3;
  f16* gp = dst + (size_t)((b << 10) + pblk * 32 + row) * HID + seg * 32;
  #pragma unroll
  for (int j = 0; j < 4; j++)
    *(f16x8*)(gp + j * 8) = *(const f16x8*)&bounce[row * 136 + seg * 32 + j * 8];
}

// ----------------------------- baseb1 = W1[:,0:128] @ g + b1, fp32 out
__global__ __launch_bounds__(256) void posproj_k(
    const f16* __restrict__ g, const f16* __restrict__ W1_h,
    const float* __restrict__ b1, float* __restrict__ baseb1) {
  __shared__ f16 As[32 * 136];
  __shared__ f16 Wls[128 * 136];
  int b = blockIdx.x >> 5, y = blockIdx.x & 31;
  int tid = threadIdx.x, lane = tid & 63, wv = tid >> 6;
  int q = lane >> 4, lr = lane & 15;
  int nq = wv * 32;
  int pbase = (b << 10) + (y << 5);
  {
    int row = tid >> 3, col = (tid & 7) * 16;
    *(f16x8*)&As[row * 136 + col]     = *(const f16x8*)(g + (size_t)(pbase + row) * HID + col);
    *(f16x8*)&As[row * 136 + col + 8] = *(const f16x8*)(g + (size_t)(pbase + row) * HID + col + 8);
  }
  {
    int o = tid >> 1, half = (tid & 1) * 64;
    #pragma unroll
    for (int j = 0; j < 8; j++)
      *(f16x8*)&Wls[o * 136 + half + j * 8] = *(const f16x8*)(W1_h + o * 512 + half + j * 8);
  }
  __syncthreads();
  f32x4 acc[2][2];
  #pragma unroll
  for (int i = 0; i < 2; i++)
    #pragma unroll
    for (int j = 0; j < 2; j++) acc[i][j] = (f32x4){0.f, 0.f, 0.f, 0.f};
  #pragma unroll
  for (int k0 = 0; k0 < 128; k0 += 32) {
    f16x8 a0 = *(const f16x8*)&As[(lr) * 136 + k0 + q * 8];
    f16x8 a1 = *(const f16x8*)&As[(16 + lr) * 136 + k0 + q * 8];
    f16x8 b0 = *(const f16x8*)&Wls[(nq + lr) * 136 + k0 + q * 8];
    f16x8 b1v = *(const f16x8*)&Wls[(nq + 16 + lr) * 136 + k0 + q * 8];
    acc[0][0] = MFMA16(a0, b0, acc[0][0]); acc[0][1] = MFMA16(a0, b1v, acc[0][1]);
    acc[1][0] = MFMA16(a1, b0, acc[1][0]); acc[1][1] = MFMA16(a1, b1v, acc[1][1]);
  }
  #pragma unroll
  for (int mi = 0; mi < 2; mi++)
    #pragma unroll
    for (int r = 0; r < 4; r++) {
      int m = mi * 16 + q * 4 + r;
      #pragma unroll
      for (int ni = 0; ni < 2; ni++) {
        int n = nq + ni * 16 + lr;
        baseb1[(size_t)(pbase + m) * HID + n] = acc[mi][ni][r] + b1[n];
      }
    }
}

// ------------------------------------------------------------------- main
// grid (32 y, 8 b, 6 agroups) x 256 thr, 3 blocks/CU. W1[:,128:512] f16
// B-fragments in registers, reused over 6 angles. Per angle: build
// X=[qr | g.*qr | |g-qr|] with PACKED f16 math (pk_fma blend, no unpack/pack),
// 48 MFMA/wave, fused epilogue with preloaded base+b1.
__global__ __launch_bounds__(256, 3) void main_k(
    const f16* __restrict__ g_h, const f16* __restrict__ q_h,
    const float* __restrict__ baseb1, const f16* __restrict__ W1_h,
    const float* __restrict__ W2, const float* __restrict__ angles,
    float* __restrict__ out) {
  __shared__ f16 Xs[32 * 392];     // 25088 B
  __shared__ float redw[4];
  int y = blockIdx.x, b = blockIdx.y;
  int tid = threadIdx.x;
  int lane = tid & 63, wv = tid >> 6;
  int q = lane >> 4, lr = lane & 15;
  int nq = wv * 32;

  // ---- B-fragments from global f16 W1 (cols 128..512), once per block
  f16x8 bfr[12][2];
  #pragma unroll
  for (int s = 0; s < 12; s++)
    #pragma unroll
    for (int ni = 0; ni < 2; ni++) {
      int o = nq + ni * 16 + lr;
      bfr[s][ni] = *(const f16x8*)(W1_h + o * 512 + 128 + s * 32 + q * 8);
    }

  // ---- preload base+b1 and W2 (angle-invariant lane mapping)
  float bacc[2][2][4];
  float w2v[2];
  #pragma unroll
  for (int ni = 0; ni < 2; ni++) w2v[ni] = W2[nq + ni * 16 + lr];
  #pragma unroll
  for (int mi = 0; mi < 2; mi++)
    #pragma unroll
    for (int r = 0; r < 4; r++) {
      int m = mi * 16 + q * 4 + r;
      #pragma unroll
      for (int ni = 0; ni < 2; ni++)
        bacc[mi][ni][r] = baseb1[(size_t)((b << 10) + (y << 5) + m) * HID + nq + ni * 16 + lr];
    }

  // build-phase constants: 8 threads per position row
  int bx = tid >> 3, ks = tid & 7;
  const f16* qB = q_h + (size_t)(b << 10) * HID;
  const f16* gB = g_h + (size_t)((b << 10) + (y << 5) + bx) * HID;

  for (int it = 0; it < 6; it++) {
    int a = blockIdx.z * 6 + it;
    float th = angles[a] * 0.017453292519943295f;
    float ct = cosf(th), st = sinf(th);

    // ---- build X = [qr | g.*qr | |g-qr|]  (32 pos x 384) in packed f16
    {
      float w4[4]; int p4[4];
      rot_corners(ct, st, y, bx, w4, p4);
      f16x2 wc[4];
      #pragma unroll
      for (int k = 0; k < 4; k++) {
        f16 h = (f16)w4[k];
        wc[k] = (f16x2){h, h};
      }
      const f16* c0p = qB + p4[0] * HID;
      const f16* c1p = qB + p4[1] * HID;
      const f16* c2p = qB + p4[2] * HID;
      const f16* c3p = qB + p4[3] * HID;
      #pragma unroll
      for (int cg = 0; cg < 2; cg++) {
        int c = ks * 16 + cg * 8;
        union U8 { f16x8 v; f16x2 h[4]; } u0, u1, u2, u3, gg, oq, om, oa;
        u0.v = *(const f16x8*)(c0p + c);
        u1.v = *(const f16x8*)(c1p + c);
        u2.v = *(const f16x8*)(c2p + c);
        u3.v = *(const f16x8*)(c3p + c);
        gg.v = *(const f16x8*)(gB + c);
        #pragma unroll
        for (int i = 0; i < 4; i++) {
          f16x2 qr = u0.h[i] * wc[0] + u1.h[i] * wc[1]
                   + u2.h[i] * wc[2] + u3.h[i] * wc[3];
          f16x2 mm = gg.h[i] * qr;
          union { f16x2 h; unsigned int u; } dd;
          dd.h = gg.h[i] - qr;
          dd.u &= 0x7fff7fffu;             // packed |.|
          oq.h[i] = qr; om.h[i] = mm; oa.h[i] = dd.h;
        }
        *(f16x8*)&Xs[bx * 392 + c] = oq.v;
        *(f16x8*)&Xs[bx * 392 + 128 + c] = om.v;
        *(f16x8*)&Xs[bx * 392 + 256 + c] = oa.v;
      }
    }
    __syncthreads();

    // ---- MFMA: 32x32 tile per wave (nq columns), K=384, B from registers
    f32x4 acc[2][2];
    #pragma unroll
    for (int i = 0; i < 2; i++)
      #pragma unroll
      for (int j = 0; j < 2; j++) acc[i][j] = (f32x4){0.f, 0.f, 0.f, 0.f};
    #pragma unroll
    for (int s = 0; s < 12; s++) {
      f16x8 a0 = *(const f16x8*)&Xs[(lr) * 392 + s * 32 + q * 8];
      f16x8 a1 = *(const f16x8*)&Xs[(16 + lr) * 392 + s * 32 + q * 8];
      acc[0][0] = MFMA16(a0, bfr[s][0], acc[0][0]);
      acc[0][1] = MFMA16(a0, bfr[s][1], acc[0][1]);
      acc[1][0] = MFMA16(a1, bfr[s][0], acc[1][0]);
      acc[1][1] = MFMA16(a1, bfr[s][1], acc[1][1]);
    }

    // ---- epilogue: relu(acc + base + b1) . W2, reduce, atomic
    float s = 0.f;
    #pragma unroll
    for (int mi = 0; mi < 2; mi++)
      #pragma unroll
      for (int ni = 0; ni < 2; ni++)
        #pragma unroll
        for (int r = 0; r < 4; r++)
          s = fmaf(w2v[ni], fmaxf(acc[mi][ni][r] + bacc[mi][ni][r], 0.f), s);
    #pragma unroll
    for (int off = 32; off > 0; off >>= 1) s += __shfl_down(s, off, 64);
    if (lane == 0) redw[wv] = s;
    __syncthreads();   // guards redw AND Xs reuse next iteration
    if (tid == 0) {
      float tot = redw[0] + redw[1] + redw[2] + redw[3];
      atomicAdd(&out[b * NA + a], tot * (1.0f / 1024.0f));
    }
  }
}

// --------------------------------------------------------------------- launch
extern "C" void kernel_launch(void* const* d_in, const int* in_sizes, int n_in,
                              void* d_out, int out_size, void* d_ws, size_t ws_size,
                              hipStream_t stream) {
  const float* gal = (const float*)d_in[0];
  const float* qry = (const float*)d_in[1];
  const float* Wg  = (const float*)d_in[2];
  const float* Wq  = (const float*)d_in[3];
  const float* W1  = (const float*)d_in[4];
  const float* b1  = (const float*)d_in[5];
  const float* W2  = (const float*)d_in[6];
  const float* b2  = (const float*)d_in[7];
  const float* ang = (const float*)d_in[8];
  float* out = (float*)d_out;
  char* ws = (char*)d_ws;
  f16*   g_h    = (f16*)ws;                              // 2 MB
  f16*   q_h    = (f16*)(ws + (2u << 20));               // 2 MB
  float* baseb1 = (float*)(ws + (4u << 20));             // 4 MB
  f16*   Wg_h   = (f16*)(ws + (8u << 20));               // 192 KB
  f16*   Wq_h   = (f16*)(ws + (8u << 20) + 196608);      // 192 KB
  f16*   W1_h   = (f16*)(ws + (8u << 20) + 393216);      // 128 KB

  hipLaunchKernelGGL(prep_k, dim3(128), dim3(256), 0, stream,
                     Wg, Wq, W1, b2, Wg_h, Wq_h, W1_h, out);
  hipLaunchKernelGGL(proj_norm_k, dim3(32, 8, 2), dim3(128), 0, stream,
                     gal, qry, Wg_h, Wq_h, g_h, q_h);
  hipLaunchKernelGGL(posproj_k, dim3(256), dim3(256), 0, stream,
                     g_h, W1_h, b1, baseb1);
  hipLaunchKernelGGL(main_k, dim3(32, 8, 6), dim3(256), 0, stream,
                     g_h, q_h, baseb1, W1_h, W2, ang, out);
}

// Round 6
// 167.635 us; speedup vs baseline: 3.6490x; 1.0423x over previous
//
#include <hip/hip_runtime.h>
#include <math.h>

#define B_   8
#define CIN  768
#define HID  128
#define NA   36
#define PP   1024

typedef _Float16 f16;
typedef __attribute__((ext_vector_type(2))) _Float16 f16x2;
typedef __attribute__((ext_vector_type(4))) _Float16 f16x4;
typedef __attribute__((ext_vector_type(8))) _Float16 f16x8;
typedef __attribute__((ext_vector_type(4))) float f32x4;

#define MFMA16(a, b, c) __builtin_amdgcn_mfma_f32_16x16x32_f16((a), (b), (c), 0, 0, 0)

__device__ inline f16x2 pkrtz(float a, float b) {
  union { __fp16 __attribute__((ext_vector_type(2))) r; f16x2 h; } u;
  u.r = __builtin_amdgcn_cvt_pkrtz(a, b);
  return u.h;
}

// ------------------------------------------------- rotation corner helper
__device__ inline void rot_corners(float ct, float st, int y, int x,
                                   float w[4], int p[4]) {
  float xn = (2.0f * x + 1.0f) * (1.0f / 32.0f) - 1.0f;
  float yn = (2.0f * y + 1.0f) * (1.0f / 32.0f) - 1.0f;
  float gx = ct * xn - st * yn;
  float gy = st * xn + ct * yn;
  float ix = ((gx + 1.0f) * 32.0f - 1.0f) * 0.5f;
  float iy = ((gy + 1.0f) * 32.0f - 1.0f) * 0.5f;
  float x0f = floorf(ix), y0f = floorf(iy);
  float wx = ix - x0f, wy = iy - y0f;
  int x0 = (int)x0f, y0 = (int)y0f;
  int x1 = x0 + 1, y1 = y0 + 1;
  float vx0 = (x0 >= 0 && x0 < 32) ? 1.0f : 0.0f;
  float vx1 = (x1 >= 0 && x1 < 32) ? 1.0f : 0.0f;
  float vy0 = (y0 >= 0 && y0 < 32) ? 1.0f : 0.0f;
  float vy1 = (y1 >= 0 && y1 < 32) ? 1.0f : 0.0f;
  int cx0 = min(max(x0, 0), 31), cx1 = min(max(x1, 0), 31);
  int cy0 = min(max(y0, 0), 31), cy1 = min(max(y1, 0), 31);
  w[0] = (1.0f - wx) * (1.0f - wy) * vx0 * vy0;  p[0] = (cy0 << 5) + cx0;
  w[1] = wx * (1.0f - wy) * vx1 * vy0;           p[1] = (cy0 << 5) + cx1;
  w[2] = (1.0f - wx) * wy * vx0 * vy1;           p[2] = (cy1 << 5) + cx0;
  w[3] = wx * wy * vx1 * vy1;                    p[3] = (cy1 << 5) + cx1;
}

// -------------------------------------------------------------------- prep
__global__ __launch_bounds__(256) void prep_k(
    const float* __restrict__ Wg, const float* __restrict__ Wq,
    const float* __restrict__ W1, const float* __restrict__ b2,
    f16* __restrict__ Wg_h, f16* __restrict__ Wq_h,
    f16* __restrict__ W1_h, float* __restrict__ out) {
  int idx = blockIdx.x * 256 + threadIdx.x;
  if (idx < B_ * NA) out[idx] = b2[0];
  if (idx < 32768) {
    int e = idx * 8;
    const float* src; f16* dst; int off;
    if (e < 98304)       { src = Wg; dst = Wg_h; off = e; }
    else if (e < 196608) { src = Wq; dst = Wq_h; off = e - 98304; }
    else                 { src = W1; dst = W1_h; off = e - 196608; }
    float4 lo = *(const float4*)(src + off);
    float4 hi = *(const float4*)(src + off + 4);
    f16x8 h;
    h[0] = (f16)lo.x; h[1] = (f16)lo.y; h[2] = (f16)lo.z; h[3] = (f16)lo.w;
    h[4] = (f16)hi.x; h[5] = (f16)hi.y; h[6] = (f16)hi.z; h[7] = (f16)hi.w;
    *(f16x8*)(dst + off) = h;
  }
}

// -------------------------------------------------- fused projection kernel
// grid (32 pblk, 8 b, 2 img) x 512 thr (8 waves = 4 K-split x 2 M-split).
// Phase 1: C[o,p] = W @ img for 32 positions, K=768 split 4-way across waves,
//          W staged in LDS chunks of 256 K, image B-frags direct from global.
// Phase 2: psums combined in LDS, l2-norm over o, f16 store.
// Phase 3 (gallery only): baseb1 = W1[:,0:128] @ gn + b1 (N-split GEMM).
#define WCH_S 264   /* f16 row stride of W chunk  */
#define PS_S  132   /* fp32 row stride of psum    */
#define GN_S  136   /* f16 row stride of Gn / W1l */
__global__ __launch_bounds__(512, 4) void projfused_k(
    const float* __restrict__ gal, const float* __restrict__ qry,
    const f16* __restrict__ Wg_h, const f16* __restrict__ Wq_h,
    const f16* __restrict__ W1_h, const float* __restrict__ b1,
    f16* __restrict__ gout, f16* __restrict__ qout,
    float* __restrict__ baseb1) {
  __shared__ __align__(16) char LDSU[67584];
  f16*   Wch = (f16*)LDSU;            // [128][264]
  float* ps  = (float*)LDSU;          // [4][32][132]
  f16*   Gn  = (f16*)LDSU;            // [32][136]
  f16*   W1l = (f16*)(LDSU + 8704);   // [128][136]

  int pblk = blockIdx.x, b = blockIdx.y, z = blockIdx.z;
  const float* imgB = (z ? qry : gal) + (size_t)b * CIN * PP;
  const f16* Wm = z ? Wq_h : Wg_h;
  f16* dst = z ? qout : gout;
  int tid = threadIdx.x, lane = tid & 63, wv = tid >> 6;
  int q = lane >> 4, lr = lane & 15;
  int kw = wv & 3, mw = wv >> 2;
  int pw = pblk * 32 + mw * 16;       // wave's base position

  f32x4 acc[8];
  #pragma unroll
  for (int t = 0; t < 8; t++) acc[t] = (f32x4){0.f, 0.f, 0.f, 0.f};

  int so = tid >> 2, sseg = (tid & 3) * 64;    // W staging coords
  for (int cc = 0; cc < CIN; cc += 256) {
    #pragma unroll
    for (int j = 0; j < 8; j++)
      *(f16x8*)&Wch[so * WCH_S + sseg + j * 8] =
          *(const f16x8*)(Wm + so * CIN + cc + sseg + j * 8);
    __syncthreads();
    #pragma unroll
    for (int ks = 0; ks < 2; ks++) {
      int k0 = kw * 64 + ks * 32;
      const float* ip = imgB + (size_t)(cc + k0 + q * 8) * PP + pw + lr;
      float v0 = ip[0], v1 = ip[PP], v2 = ip[2 * PP], v3 = ip[3 * PP];
      float v4 = ip[4 * PP], v5 = ip[5 * PP], v6 = ip[6 * PP], v7 = ip[7 * PP];
      union { f16x8 v; f16x2 h[4]; } bf;
      bf.h[0] = pkrtz(v0, v1); bf.h[1] = pkrtz(v2, v3);
      bf.h[2] = pkrtz(v4, v5); bf.h[3] = pkrtz(v6, v7);
      #pragma unroll
      for (int og = 0; og < 8; og++) {
        f16x8 af = *(const f16x8*)&Wch[(og * 16 + lr) * WCH_S + k0 + q * 8];
        acc[og] = MFMA16(af, bf.v, acc[og]);
      }
    }
    __syncthreads();   // WAR before restage (and before psum overlay)
  }

  // ---- phase 2: psum -> LDS, combine, l2 norm, store
  #pragma unroll
  for (int og = 0; og < 8; og++)
    *(f32x4*)&ps[kw * (32 * PS_S) + (mw * 16 + lr) * PS_S + og * 16 + q * 4] = acc[og];
  __syncthreads();
  int pos = tid >> 4, oo = (tid & 15) * 8;
  f32x4 v0s = (f32x4){0.f,0.f,0.f,0.f}, v1s = (f32x4){0.f,0.f,0.f,0.f};
  #pragma unroll
  for (int k = 0; k < 4; k++) {
    v0s += *(const f32x4*)&ps[k * (32 * PS_S) + pos * PS_S + oo];
    v1s += *(const f32x4*)&ps[k * (32 * PS_S) + pos * PS_S + oo + 4];
  }
  float ss = v0s.x*v0s.x + v0s.y*v0s.y + v0s.z*v0s.z + v0s.w*v0s.w
           + v1s.x*v1s.x + v1s.y*v1s.y + v1s.z*v1s.z + v1s.w*v1s.w;
  ss += __shfl_xor(ss, 1); ss += __shfl_xor(ss, 2);
  ss += __shfl_xor(ss, 4); ss += __shfl_xor(ss, 8);
  float inv = 1.0f / fmaxf(sqrtf(ss), 1e-12f);
  f16x8 gn8;
  gn8[0] = (f16)(v0s.x*inv); gn8[1] = (f16)(v0s.y*inv);
  gn8[2] = (f16)(v0s.z*inv); gn8[3] = (f16)(v0s.w*inv);
  gn8[4] = (f16)(v1s.x*inv); gn8[5] = (f16)(v1s.y*inv);
  gn8[6] = (f16)(v1s.z*inv); gn8[7] = (f16)(v1s.w*inv);
  *(f16x8*)(dst + (size_t)((b << 10) + pblk * 32 + pos) * HID + oo) = gn8;

  // ---- phase 3 (gallery only): baseb1 = W1[:,0:128] @ gn + b1
  if (z == 0) {
    __syncthreads();                 // ps reads done -> safe to overlay Gn/W1l
    *(f16x8*)&Gn[pos * GN_S + oo] = gn8;
    {
      int o = tid >> 2, seg = (tid & 3) * 32;
      #pragma unroll
      for (int j = 0; j < 4; j++)
        *(f16x8*)&W1l[o * GN_S + seg + j * 8] =
            *(const f16x8*)(W1_h + o * 512 + seg + j * 8);
    }
    __syncthreads();
    int nw = wv & 3, mw2 = wv >> 2;
    f32x4 acc2[2];
    acc2[0] = (f32x4){0.f,0.f,0.f,0.f}; acc2[1] = (f32x4){0.f,0.f,0.f,0.f};
    #pragma unroll
    for (int ks = 0; ks < 4; ks++) {
      f16x8 bfv = *(const f16x8*)&Gn[(mw2 * 16 + lr) * GN_S + ks * 32 + q * 8];
      #pragma unroll
      for (int og2 = 0; og2 < 2; og2++) {
        f16x8 af = *(const f16x8*)&W1l[(nw * 32 + og2 * 16 + lr) * GN_S + ks * 32 + q * 8];
        acc2[og2] = MFMA16(af, bfv, acc2[og2]);
      }
    }
    #pragma unroll
    for (int og2 = 0; og2 < 2; og2++) {
      int o0 = nw * 32 + og2 * 16 + q * 4;
      float4 bb = *(const float4*)(b1 + o0);
      float4 r;
      r.x = acc2[og2][0] + bb.x; r.y = acc2[og2][1] + bb.y;
      r.z = acc2[og2][2] + bb.z; r.w = acc2[og2][3] + bb.w;
      *(float4*)(baseb1 + (size_t)((b << 10) + pblk * 32 + mw2 * 16 + lr) * HID + o0) = r;
    }
  }
}

// ------------------------------------------------------------------- main
// grid (32 y, 8 b, 6 ag) x 256 thr, 3 blocks/CU. Double-buffered X (ONE
// barrier per angle); per-angle sums deferred to registers, single reduction
// + atomic at end. W1[:,128:512] f16 B-frags from global (L2-hot).
__global__ __launch_bounds__(256, 3) void main_k(
    const f16* __restrict__ g_h, const f16* __restrict__ q_h,
    const float* __restrict__ baseb1, const f16* __restrict__ W1_h,
    const float* __restrict__ W2, const float* __restrict__ angles,
    float* __restrict__ out) {
  __shared__ f16 Xs[2][32 * 392];
  __shared__ float redl[24];
  int y = blockIdx.x, b = blockIdx.y;
  int tid = threadIdx.x;
  int lane = tid & 63, wv = tid >> 6;
  int q = lane >> 4, lr = lane & 15;
  int nq = wv * 32;

  f16x8 bfr[12][2];
  #pragma unroll
  for (int s = 0; s < 12; s++)
    #pragma unroll
    for (int ni = 0; ni < 2; ni++) {
      int o = nq + ni * 16 + lr;
      bfr[s][ni] = *(const f16x8*)(W1_h + o * 512 + 128 + s * 32 + q * 8);
    }

  float bacc[2][2][4];
  float w2v[2];
  #pragma unroll
  for (int ni = 0; ni < 2; ni++) w2v[ni] = W2[nq + ni * 16 + lr];
  #pragma unroll
  for (int mi = 0; mi < 2; mi++)
    #pragma unroll
    for (int r = 0; r < 4; r++) {
      int m = mi * 16 + q * 4 + r;
      #pragma unroll
      for (int ni = 0; ni < 2; ni++)
        bacc[mi][ni][r] = baseb1[(size_t)((b << 10) + (y << 5) + m) * HID + nq + ni * 16 + lr];
    }

  int bx = tid >> 3, ks = tid & 7;
  const f16* qB = q_h + (size_t)(b << 10) * HID;
  const f16* gB = g_h + (size_t)((b << 10) + (y << 5) + bx) * HID;

  float spart[6];

  for (int it = 0; it < 6; it++) {
    int a = blockIdx.z * 6 + it;
    float th = angles[a] * 0.017453292519943295f;
    float ct = cosf(th), st = sinf(th);
    f16* Xb = &Xs[it & 1][0];

    // ---- build X = [qr | g.*qr | |g-qr|] (32 pos x 384), packed f16
    {
      float w4[4]; int p4[4];
      rot_corners(ct, st, y, bx, w4, p4);
      f16x2 wc[4];
      #pragma unroll
      for (int k = 0; k < 4; k++) {
        f16 h = (f16)w4[k];
        wc[k] = (f16x2){h, h};
      }
      const f16* c0p = qB + p4[0] * HID;
      const f16* c1p = qB + p4[1] * HID;
      const f16* c2p = qB + p4[2] * HID;
      const f16* c3p = qB + p4[3] * HID;
      #pragma unroll
      for (int cg = 0; cg < 2; cg++) {
        int c = ks * 16 + cg * 8;
        union U8 { f16x8 v; f16x2 h[4]; } u0, u1, u2, u3, gg, oq, om, oa;
        u0.v = *(const f16x8*)(c0p + c);
        u1.v = *(const f16x8*)(c1p + c);
        u2.v = *(const f16x8*)(c2p + c);
        u3.v = *(const f16x8*)(c3p + c);
        gg.v = *(const f16x8*)(gB + c);
        #pragma unroll
        for (int i = 0; i < 4; i++) {
          f16x2 qr = u0.h[i] * wc[0] + u1.h[i] * wc[1]
                   + u2.h[i] * wc[2] + u3.h[i] * wc[3];
          f16x2 mm = gg.h[i] * qr;
          union { f16x2 h; unsigned int u; } dd;
          dd.h = gg.h[i] - qr;
          dd.u &= 0x7fff7fffu;
          oq.h[i] = qr; om.h[i] = mm; oa.h[i] = dd.h;
        }
        *(f16x8*)&Xb[bx * 392 + c] = oq.v;
        *(f16x8*)&Xb[bx * 392 + 128 + c] = om.v;
        *(f16x8*)&Xb[bx * 392 + 256 + c] = oa.v;
      }
    }
    __syncthreads();   // the ONLY barrier per angle (dbuf makes WAR safe)

    f32x4 acc[2][2];
    #pragma unroll
    for (int i = 0; i < 2; i++)
      #pragma unroll
      for (int j = 0; j < 2; j++) acc[i][j] = (f32x4){0.f, 0.f, 0.f, 0.f};
    #pragma unroll
    for (int s = 0; s < 12; s++) {
      f16x8 a0 = *(const f16x8*)&Xb[(lr) * 392 + s * 32 + q * 8];
      f16x8 a1 = *(const f16x8*)&Xb[(16 + lr) * 392 + s * 32 + q * 8];
      acc[0][0] = MFMA16(a0, bfr[s][0], acc[0][0]);
      acc[0][1] = MFMA16(a0, bfr[s][1], acc[0][1]);
      acc[1][0] = MFMA16(a1, bfr[s][0], acc[1][0]);
      acc[1][1] = MFMA16(a1, bfr[s][1], acc[1][1]);
    }

    float s = 0.f;
    #pragma unroll
    for (int mi = 0; mi < 2; mi++)
      #pragma unroll
      for (int ni = 0; ni < 2; ni++)
        #pragma unroll
        for (int r = 0; r < 4; r++)
          s = fmaf(w2v[ni], fmaxf(acc[mi][ni][r] + bacc[mi][ni][r], 0.f), s);
    spart[it] = s;
  }

  // ---- one reduction + atomic for all 6 angles
  #pragma unroll
  for (int it = 0; it < 6; it++) {
    float v = spart[it];
    #pragma unroll
    for (int off = 32; off > 0; off >>= 1) v += __shfl_down(v, off, 64);
    if (lane == 0) redl[wv * 6 + it] = v;
  }
  __syncthreads();
  if (tid < 6) {
    float tot = redl[tid] + redl[6 + tid] + redl[12 + tid] + redl[18 + tid];
    atomicAdd(&out[b * NA + blockIdx.z * 6 + tid], tot * (1.0f / 1024.0f));
  }
}

// --------------------------------------------------------------------- launch
extern "C" void kernel_launch(void* const* d_in, const int* in_sizes, int n_in,
                              void* d_out, int out_size, void* d_ws, size_t ws_size,
                              hipStream_t stream) {
  const float* gal = (const float*)d_in[0];
  const float* qry = (const float*)d_in[1];
  const float* Wg  = (const float*)d_in[2];
  const float* Wq  = (const float*)d_in[3];
  const float* W1  = (const float*)d_in[4];
  const float* b1  = (const float*)d_in[5];
  const float* W2  = (const float*)d_in[6];
  const float* b2  = (const float*)d_in[7];
  const float* ang = (const float*)d_in[8];
  float* out = (float*)d_out;
  char* ws = (char*)d_ws;
  f16*   g_h    = (f16*)ws;                              // 2 MB
  f16*   q_h    = (f16*)(ws + (2u << 20));               // 2 MB
  float* baseb1 = (float*)(ws + (4u << 20));             // 4 MB
  f16*   Wg_h   = (f16*)(ws + (8u << 20));               // 192 KB
  f16*   Wq_h   = (f16*)(ws + (8u << 20) + 196608);      // 192 KB
  f16*   W1_h   = (f16*)(ws + (8u << 20) + 393216);      // 128 KB

  hipLaunchKernelGGL(prep_k, dim3(128), dim3(256), 0, stream,
                     Wg, Wq, W1, b2, Wg_h, Wq_h, W1_h, out);
  hipLaunchKernelGGL(projfused_k, dim3(32, 8, 2), dim3(512), 0, stream,
                     gal, qry, Wg_h, Wq_h, W1_h, b1, g_h, q_h, baseb1);
  hipLaunchKernelGGL(main_k, dim3(32, 8, 6), dim3(256), 0, stream,
                     g_h, q_h, baseb1, W1_h, W2, ang, out);
}

// Round 7
// 163.136 us; speedup vs baseline: 3.7497x; 1.0276x over previous
//
#include <hip/hip_runtime.h>
#include <math.h>

#define B_   8
#define CIN  768
#define HID  128
#define NA   36
#define PP   1024

typedef _Float16 f16;
typedef __attribute__((ext_vector_type(2))) _Float16 f16x2;
typedef __attribute__((ext_vector_type(4))) _Float16 f16x4;
typedef __attribute__((ext_vector_type(8))) _Float16 f16x8;
typedef __attribute__((ext_vector_type(4))) float f32x4;

#define MFMA16(a, b, c) __builtin_amdgcn_mfma_f32_16x16x32_f16((a), (b), (c), 0, 0, 0)

__device__ inline f16x2 pkrtz(float a, float b) {
  union { __fp16 __attribute__((ext_vector_type(2))) r; f16x2 h; } u;
  u.r = __builtin_amdgcn_cvt_pkrtz(a, b);
  return u.h;
}

// ------------------------------------------------- rotation corner helper
__device__ inline void rot_corners(float ct, float st, int y, int x,
                                   float w[4], int p[4]) {
  float xn = (2.0f * x + 1.0f) * (1.0f / 32.0f) - 1.0f;
  float yn = (2.0f * y + 1.0f) * (1.0f / 32.0f) - 1.0f;
  float gx = ct * xn - st * yn;
  float gy = st * xn + ct * yn;
  float ix = ((gx + 1.0f) * 32.0f - 1.0f) * 0.5f;
  float iy = ((gy + 1.0f) * 32.0f - 1.0f) * 0.5f;
  float x0f = floorf(ix), y0f = floorf(iy);
  float wx = ix - x0f, wy = iy - y0f;
  int x0 = (int)x0f, y0 = (int)y0f;
  int x1 = x0 + 1, y1 = y0 + 1;
  float vx0 = (x0 >= 0 && x0 < 32) ? 1.0f : 0.0f;
  float vx1 = (x1 >= 0 && x1 < 32) ? 1.0f : 0.0f;
  float vy0 = (y0 >= 0 && y0 < 32) ? 1.0f : 0.0f;
  float vy1 = (y1 >= 0 && y1 < 32) ? 1.0f : 0.0f;
  int cx0 = min(max(x0, 0), 31), cx1 = min(max(x1, 0), 31);
  int cy0 = min(max(y0, 0), 31), cy1 = min(max(y1, 0), 31);
  w[0] = (1.0f - wx) * (1.0f - wy) * vx0 * vy0;  p[0] = (cy0 << 5) + cx0;
  w[1] = wx * (1.0f - wy) * vx1 * vy0;           p[1] = (cy0 << 5) + cx1;
  w[2] = (1.0f - wx) * wy * vx0 * vy1;           p[2] = (cy1 << 5) + cx0;
  w[3] = wx * wy * vx1 * vy1;                    p[3] = (cy1 << 5) + cx1;
}

// -------------------------------------------------------------------- prep
__global__ __launch_bounds__(256) void prep_k(
    const float* __restrict__ Wg, const float* __restrict__ Wq,
    const float* __restrict__ W1, const float* __restrict__ b2,
    f16* __restrict__ Wg_h, f16* __restrict__ Wq_h,
    f16* __restrict__ W1_h, float* __restrict__ out) {
  int idx = blockIdx.x * 256 + threadIdx.x;
  if (idx < B_ * NA) out[idx] = b2[0];
  if (idx < 32768) {
    int e = idx * 8;
    const float* src; f16* dst; int off;
    if (e < 98304)       { src = Wg; dst = Wg_h; off = e; }
    else if (e < 196608) { src = Wq; dst = Wq_h; off = e - 98304; }
    else                 { src = W1; dst = W1_h; off = e - 196608; }
    float4 lo = *(const float4*)(src + off);
    float4 hi = *(const float4*)(src + off + 4);
    f16x8 h;
    h[0] = (f16)lo.x; h[1] = (f16)lo.y; h[2] = (f16)lo.z; h[3] = (f16)lo.w;
    h[4] = (f16)hi.x; h[5] = (f16)hi.y; h[6] = (f16)hi.z; h[7] = (f16)hi.w;
    *(f16x8*)(dst + off) = h;
  }
}

// -------------------------------------------------- fused projection kernel
// grid (32 pblk, 8 b, 2 img) x 512 thr (8 waves = 4 K-split x 2 M-split).
// Image loads software-pipelined one 256-K chunk ahead (in registers).
#define WCH_S 264
#define PS_S  132
#define GN_S  136
__global__ __launch_bounds__(512, 4) void projfused_k(
    const float* __restrict__ gal, const float* __restrict__ qry,
    const f16* __restrict__ Wg_h, const f16* __restrict__ Wq_h,
    const f16* __restrict__ W1_h, const float* __restrict__ b1,
    f16* __restrict__ gout, f16* __restrict__ qout,
    float* __restrict__ baseb1) {
  __shared__ __align__(16) char LDSU[67584];
  f16*   Wch = (f16*)LDSU;            // [128][264]
  float* ps  = (float*)LDSU;          // [4][32][132]
  f16*   Gn  = (f16*)LDSU;            // [32][136]
  f16*   W1l = (f16*)(LDSU + 8704);   // [128][136]

  int pblk = blockIdx.x, b = blockIdx.y, z = blockIdx.z;
  const float* imgB = (z ? qry : gal) + (size_t)b * CIN * PP;
  const f16* Wm = z ? Wq_h : Wg_h;
  f16* dst = z ? qout : gout;
  int tid = threadIdx.x, lane = tid & 63, wv = tid >> 6;
  int q = lane >> 4, lr = lane & 15;
  int kw = wv & 3, mw = wv >> 2;
  int pw = pblk * 32 + mw * 16;

  f32x4 acc[8];
  #pragma unroll
  for (int t = 0; t < 8; t++) acc[t] = (f32x4){0.f, 0.f, 0.f, 0.f};

  int so = tid >> 2, sseg = (tid & 3) * 64;
  const float* ipb = imgB + (size_t)(kw * 64 + q * 8) * PP + pw + lr;

  float fim[2][16];
  #pragma unroll
  for (int t = 0; t < 16; t++)                 // prologue: chunk 0 loads
    fim[0][t] = ipb[(size_t)((t >> 3) * 32 + (t & 7)) * PP];

  #pragma unroll
  for (int c3 = 0; c3 < 3; c3++) {
    int cc = c3 << 8;
    f16x8 w8[8];                               // stage reads into regs
    #pragma unroll
    for (int j = 0; j < 8; j++)
      w8[j] = *(const f16x8*)(Wm + so * CIN + cc + sseg + j * 8);
    if (c3 < 2) {                              // prefetch next image chunk
      #pragma unroll
      for (int t = 0; t < 16; t++)
        fim[(c3 + 1) & 1][t] =
            ipb[(size_t)(((c3 + 1) << 8) + (t >> 3) * 32 + (t & 7)) * PP];
    }
    #pragma unroll
    for (int j = 0; j < 8; j++)                // stage writes
      *(f16x8*)&Wch[so * WCH_S + sseg + j * 8] = w8[j];
    __syncthreads();
    #pragma unroll
    for (int ksi = 0; ksi < 2; ksi++) {
      union { f16x8 v; f16x2 h[4]; } bf;
      const float* fp = &fim[c3 & 1][ksi * 8];
      bf.h[0] = pkrtz(fp[0], fp[1]); bf.h[1] = pkrtz(fp[2], fp[3]);
      bf.h[2] = pkrtz(fp[4], fp[5]); bf.h[3] = pkrtz(fp[6], fp[7]);
      int k0 = kw * 64 + ksi * 32;
      #pragma unroll
      for (int og = 0; og < 8; og++) {
        f16x8 af = *(const f16x8*)&Wch[(og * 16 + lr) * WCH_S + k0 + q * 8];
        acc[og] = MFMA16(af, bf.v, acc[og]);
      }
    }
    __syncthreads();
  }

  // ---- phase 2: psum -> LDS, combine, l2 norm, store
  #pragma unroll
  for (int og = 0; og < 8; og++)
    *(f32x4*)&ps[kw * (32 * PS_S) + (mw * 16 + lr) * PS_S + og * 16 + q * 4] = acc[og];
  __syncthreads();
  int pos = tid >> 4, oo = (tid & 15) * 8;
  f32x4 v0s = (f32x4){0.f,0.f,0.f,0.f}, v1s = (f32x4){0.f,0.f,0.f,0.f};
  #pragma unroll
  for (int k = 0; k < 4; k++) {
    v0s += *(const f32x4*)&ps[k * (32 * PS_S) + pos * PS_S + oo];
    v1s += *(const f32x4*)&ps[k * (32 * PS_S) + pos * PS_S + oo + 4];
  }
  float ss = v0s.x*v0s.x + v0s.y*v0s.y + v0s.z*v0s.z + v0s.w*v0s.w
           + v1s.x*v1s.x + v1s.y*v1s.y + v1s.z*v1s.z + v1s.w*v1s.w;
  ss += __shfl_xor(ss, 1); ss += __shfl_xor(ss, 2);
  ss += __shfl_xor(ss, 4); ss += __shfl_xor(ss, 8);
  float inv = 1.0f / fmaxf(sqrtf(ss), 1e-12f);
  f16x8 gn8;
  gn8[0] = (f16)(v0s.x*inv); gn8[1] = (f16)(v0s.y*inv);
  gn8[2] = (f16)(v0s.z*inv); gn8[3] = (f16)(v0s.w*inv);
  gn8[4] = (f16)(v1s.x*inv); gn8[5] = (f16)(v1s.y*inv);
  gn8[6] = (f16)(v1s.z*inv); gn8[7] = (f16)(v1s.w*inv);
  *(f16x8*)(dst + (size_t)((b << 10) + pblk * 32 + pos) * HID + oo) = gn8;

  // ---- phase 3 (gallery only): baseb1 = W1[:,0:128] @ gn + b1
  if (z == 0) {
    __syncthreads();
    *(f16x8*)&Gn[pos * GN_S + oo] = gn8;
    {
      int o = tid >> 2, seg = (tid & 3) * 32;
      #pragma unroll
      for (int j = 0; j < 4; j++)
        *(f16x8*)&W1l[o * GN_S + seg + j * 8] =
            *(const f16x8*)(W1_h + o * 512 + seg + j * 8);
    }
    __syncthreads();
    int nw = wv & 3, mw2 = wv >> 2;
    f32x4 acc2[2];
    acc2[0] = (f32x4){0.f,0.f,0.f,0.f}; acc2[1] = (f32x4){0.f,0.f,0.f,0.f};
    #pragma unroll
    for (int ksj = 0; ksj < 4; ksj++) {
      f16x8 bfv = *(const f16x8*)&Gn[(mw2 * 16 + lr) * GN_S + ksj * 32 + q * 8];
      #pragma unroll
      for (int og2 = 0; og2 < 2; og2++) {
        f16x8 af = *(const f16x8*)&W1l[(nw * 32 + og2 * 16 + lr) * GN_S + ksj * 32 + q * 8];
        acc2[og2] = MFMA16(af, bfv, acc2[og2]);
      }
    }
    #pragma unroll
    for (int og2 = 0; og2 < 2; og2++) {
      int o0 = nw * 32 + og2 * 16 + q * 4;
      float4 bb = *(const float4*)(b1 + o0);
      float4 r;
      r.x = acc2[og2][0] + bb.x; r.y = acc2[og2][1] + bb.y;
      r.z = acc2[og2][2] + bb.z; r.w = acc2[og2][3] + bb.w;
      *(float4*)(baseb1 + (size_t)((b << 10) + pblk * 32 + mw2 * 16 + lr) * HID + o0) = r;
    }
  }
}

// ------------------------------------------------------------------- main
// grid (32 y, 8 b, 6 ag) x 256 thr, LB(256,2): ~230 VGPR so the 24 W1
// B-frags are TRULY register-resident (round-3/6 versions reloaded from L2
// every angle). Corner w/p precomputed per block into LDS tables; next
// angle's corner loads prefetched before the barrier; acc initialized from
// baseb1 via MFMA C-operand.
__global__ __launch_bounds__(256, 2) void main_k(
    const f16* __restrict__ g_h, const f16* __restrict__ q_h,
    const float* __restrict__ baseb1, const f16* __restrict__ W1_h,
    const float* __restrict__ W2, const float* __restrict__ angles,
    float* __restrict__ out) {
  __shared__ f16 Xs[2][32 * 392];
  __shared__ float wtab[6][32][4];
  __shared__ int   ptab[6][32][4];
  __shared__ float redl[24];
  int y = blockIdx.x, b = blockIdx.y;
  int tid = threadIdx.x;
  int lane = tid & 63, wv = tid >> 6;
  int q = lane >> 4, lr = lane & 15;
  int nq = wv * 32;

  // ---- corner tables: 6 angles x 32 positions, computed once
  if (tid < 192) {
    int it = tid >> 5, pos = tid & 31;
    float th = angles[blockIdx.z * 6 + it] * 0.017453292519943295f;
    float ct = cosf(th), st = sinf(th);
    float w4[4]; int p4[4];
    rot_corners(ct, st, y, pos, w4, p4);
    *(float4*)&wtab[it][pos][0] = make_float4(w4[0], w4[1], w4[2], w4[3]);
    *(int4*)&ptab[it][pos][0]   = make_int4(p4[0], p4[1], p4[2], p4[3]);
  }

  // ---- W1 B-fragments (cols 128..512) into registers, once
  f16x8 bfr[12][2];
  #pragma unroll
  for (int s = 0; s < 12; s++)
    #pragma unroll
    for (int ni = 0; ni < 2; ni++) {
      int o = nq + ni * 16 + lr;
      bfr[s][ni] = *(const f16x8*)(W1_h + o * 512 + 128 + s * 32 + q * 8);
    }

  float w2v[2];
  #pragma unroll
  for (int ni = 0; ni < 2; ni++) w2v[ni] = W2[nq + ni * 16 + lr];

  // ---- base+b1 preloaded as MFMA C-init
  f32x4 binit[2][2];
  #pragma unroll
  for (int mi = 0; mi < 2; mi++)
    #pragma unroll
    for (int ni = 0; ni < 2; ni++)
      #pragma unroll
      for (int r = 0; r < 4; r++) {
        int m = mi * 16 + q * 4 + r;
        binit[mi][ni][r] =
            baseb1[(size_t)((b << 10) + (y << 5) + m) * HID + nq + ni * 16 + lr];
      }

  int bx = tid >> 3, ks = tid & 7;
  const f16* qB = q_h + ((size_t)(b << 10)) * HID + ks * 16;
  const f16* gB = g_h + (size_t)((b << 10) + (y << 5) + bx) * HID + ks * 16;
  f16x8 gg[2] = { *(const f16x8*)gB, *(const f16x8*)(gB + 8) };

  __syncthreads();   // wtab/ptab ready

  // ---- prefetch corners for it=0
  f16x8 u[2][2][4];     // [buf][cg][corner]
  float4 wcur, wnxt;
  {
    wcur = *(const float4*)&wtab[0][bx][0];
    int4 pt = *(const int4*)&ptab[0][bx][0];
    #pragma unroll
    for (int cg = 0; cg < 2; cg++) {
      u[0][cg][0] = *(const f16x8*)(qB + pt.x * HID + cg * 8);
      u[0][cg][1] = *(const f16x8*)(qB + pt.y * HID + cg * 8);
      u[0][cg][2] = *(const f16x8*)(qB + pt.z * HID + cg * 8);
      u[0][cg][3] = *(const f16x8*)(qB + pt.w * HID + cg * 8);
    }
  }

  float spart[6];
  #pragma unroll
  for (int it = 0; it < 6; it++) {
    int cur = it & 1;
    f16* Xb = &Xs[cur][0];
    // ---- build X = [qr | g.*qr | |g-qr|] from prefetched registers
    {
      f16x2 wc[4];
      wc[0] = (f16x2){(f16)wcur.x, (f16)wcur.x};
      wc[1] = (f16x2){(f16)wcur.y, (f16)wcur.y};
      wc[2] = (f16x2){(f16)wcur.z, (f16)wcur.z};
      wc[3] = (f16x2){(f16)wcur.w, (f16)wcur.w};
      #pragma unroll
      for (int cg = 0; cg < 2; cg++) {
        int c = ks * 16 + cg * 8;
        union U8 { f16x8 v; f16x2 h[4]; } u0, u1, u2, u3, gv, oq, om, oa;
        u0.v = u[cur][cg][0]; u1.v = u[cur][cg][1];
        u2.v = u[cur][cg][2]; u3.v = u[cur][cg][3];
        gv.v = gg[cg];
        #pragma unroll
        for (int i = 0; i < 4; i++) {
          f16x2 qr = u0.h[i] * wc[0] + u1.h[i] * wc[1]
                   + u2.h[i] * wc[2] + u3.h[i] * wc[3];
          f16x2 mm = gv.h[i] * qr;
          union { f16x2 h; unsigned int uu; } dd;
          dd.h = gv.h[i] - qr;
          dd.uu &= 0x7fff7fffu;
          oq.h[i] = qr; om.h[i] = mm; oa.h[i] = dd.h;
        }
        *(f16x8*)&Xb[bx * 392 + c] = oq.v;
        *(f16x8*)&Xb[bx * 392 + 128 + c] = om.v;
        *(f16x8*)&Xb[bx * 392 + 256 + c] = oa.v;
      }
    }
    // ---- prefetch corners for it+1 (in flight during MFMA below)
    if (it < 5) {
      wnxt = *(const float4*)&wtab[it + 1][bx][0];
      int4 pt = *(const int4*)&ptab[it + 1][bx][0];
      #pragma unroll
      for (int cg = 0; cg < 2; cg++) {
        u[cur ^ 1][cg][0] = *(const f16x8*)(qB + pt.x * HID + cg * 8);
        u[cur ^ 1][cg][1] = *(const f16x8*)(qB + pt.y * HID + cg * 8);
        u[cur ^ 1][cg][2] = *(const f16x8*)(qB + pt.z * HID + cg * 8);
        u[cur ^ 1][cg][3] = *(const f16x8*)(qB + pt.w * HID + cg * 8);
      }
    }
    __syncthreads();   // single barrier per angle (dbuf)

    // ---- MFMA: C-init from baseb1, K=384, B from registers
    f32x4 a00 = binit[0][0], a01 = binit[0][1];
    f32x4 a10 = binit[1][0], a11 = binit[1][1];
    #pragma unroll
    for (int s = 0; s < 12; s++) {
      f16x8 af0 = *(const f16x8*)&Xb[(lr) * 392 + s * 32 + q * 8];
      f16x8 af1 = *(const f16x8*)&Xb[(16 + lr) * 392 + s * 32 + q * 8];
      a00 = MFMA16(af0, bfr[s][0], a00);
      a01 = MFMA16(af0, bfr[s][1], a01);
      a10 = MFMA16(af1, bfr[s][0], a10);
      a11 = MFMA16(af1, bfr[s][1], a11);
    }

    // ---- epilogue: relu . W2
    float sv = 0.f;
    #pragma unroll
    for (int r = 0; r < 4; r++) {
      sv = fmaf(w2v[0], fmaxf(a00[r], 0.f), sv);
      sv = fmaf(w2v[1], fmaxf(a01[r], 0.f), sv);
      sv = fmaf(w2v[0], fmaxf(a10[r], 0.f), sv);
      sv = fmaf(w2v[1], fmaxf(a11[r], 0.f), sv);
    }
    spart[it] = sv;
    wcur = wnxt;
  }

  // ---- one reduction + atomic for all 6 angles
  #pragma unroll
  for (int it = 0; it < 6; it++) {
    float v = spart[it];
    #pragma unroll
    for (int off = 32; off > 0; off >>= 1) v += __shfl_down(v, off, 64);
    if (lane == 0) redl[wv * 6 + it] = v;
  }
  __syncthreads();
  if (tid < 6) {
    float tot = redl[tid] + redl[6 + tid] + redl[12 + tid] + redl[18 + tid];
    atomicAdd(&out[b * NA + blockIdx.z * 6 + tid], tot * (1.0f / 1024.0f));
  }
}

// --------------------------------------------------------------------- launch
extern "C" void kernel_launch(void* const* d_in, const int* in_sizes, int n_in,
                              void* d_out, int out_size, void* d_ws, size_t ws_size,
                              hipStream_t stream) {
  const float* gal = (const float*)d_in[0];
  const float* qry = (const float*)d_in[1];
  const float* Wg  = (const float*)d_in[2];
  const float* Wq  = (const float*)d_in[3];
  const float* W1  = (const float*)d_in[4];
  const float* b1  = (const float*)d_in[5];
  const float* W2  = (const float*)d_in[6];
  const float* b2  = (const float*)d_in[7];
  const float* ang = (const float*)d_in[8];
  float* out = (float*)d_out;
  char* ws = (char*)d_ws;
  f16*   g_h    = (f16*)ws;                              // 2 MB
  f16*   q_h    = (f16*)(ws + (2u << 20));               // 2 MB
  float* baseb1 = (float*)(ws + (4u << 20));             // 4 MB
  f16*   Wg_h   = (f16*)(ws + (8u << 20));               // 192 KB
  f16*   Wq_h   = (f16*)(ws + (8u << 20) + 196608);      // 192 KB
  f16*   W1_h   = (f16*)(ws + (8u << 20) + 393216);      // 128 KB

  hipLaunchKernelGGL(prep_k, dim3(128), dim3(256), 0, stream,
                     Wg, Wq, W1, b2, Wg_h, Wq_h, W1_h, out);
  hipLaunchKernelGGL(projfused_k, dim3(32, 8, 2), dim3(512), 0, stream,
                     gal, qry, Wg_h, Wq_h, W1_h, b1, g_h, q_h, baseb1);
  hipLaunchKernelGGL(main_k, dim3(32, 8, 6), dim3(256), 0, stream,
                     g_h, q_h, baseb1, W1_h, W2, ang, out);
}